// Round 4
// baseline (4878.815 us; speedup 1.0000x reference)
//
#include <hip/hip_runtime.h>

typedef __bf16 bf16;
typedef __bf16 bf16x8 __attribute__((ext_vector_type(8)));
typedef __bf16 bf16x4 __attribute__((ext_vector_type(4)));
typedef float  f32x4  __attribute__((ext_vector_type(4)));

#define DEV __device__ __forceinline__

// async global->LDS, 16B per lane; lds dest must be wave-uniform base (HW adds lane*16)
DEV void gload_lds16(const bf16* g, bf16* l) {
    __builtin_amdgcn_global_load_lds(
        (__attribute__((address_space(1))) void*)g,
        (__attribute__((address_space(3))) void*)l, 16, 0, 0);
}

enum { M_QKV, M_SCORES, M_PV, M_RSPLIT, M_GELU, M_OUT, M_WM };

// ---------------------------------------------------------------------------
// 128x128 tile m97-structure GEMM. C[m,n] = sum_k A[m,k]*B[n,k];
// A:[M,K], B:[N,K] bf16 row-major.
// M_RSPLIT: blockIdx.z = K-split index (ksplit splits), atomicAdd into Cf.
// M_WM:     blockIdx.z = batch index, bf16 out.
// ---------------------------------------------------------------------------
template<int MODE>
__global__ __launch_bounds__(256)
void gemm_k(const bf16* __restrict__ A, const bf16* __restrict__ B,
            int M, int N, int K,
            long long batchA, long long batchB, long long batchC, int ksplit,
            const float* __restrict__ bias,
            bf16* __restrict__ Cb, float* __restrict__ Cf,
            bf16* __restrict__ qp, bf16* __restrict__ kp, bf16* __restrict__ vp)
{
    const int bm = blockIdx.x, bn = blockIdx.y, bz = blockIdx.z;
    int kTiles = K >> 5;

    const int tid = threadIdx.x, wid = tid >> 6, lane = tid & 63;
    const bf16* Ab;
    const bf16* Bb;
    if (MODE == M_RSPLIT) {
        kTiles /= ksplit;
        Ab = A + (long long)bm * 128 * K + (long long)bz * kTiles * 32;
        Bb = B + (long long)bn * 128 * K + (long long)bz * kTiles * 32;
    } else {
        Ab = A + (long long)bz * batchA + (long long)bm * 128 * K;
        Bb = B + (long long)bz * batchB + (long long)bn * 128 * K;
    }

    __shared__ __align__(16) bf16 sA[2][4096];
    __shared__ __align__(16) bf16 sB[2][4096];

    const int srow = wid * 16 + (lane >> 2);
    const int scol = (lane & 3) * 8;
    const long long aoff = (long long)srow * K + scol;

    auto stage = [&](int buf, int kt) {
        const bf16* ga = Ab + (long long)kt * 32;
        const bf16* gb = Bb + (long long)kt * 32;
        gload_lds16(ga + aoff,            &sA[buf][(wid * 16) * 32]);
        gload_lds16(ga + aoff + 64LL * K, &sA[buf][(64 + wid * 16) * 32]);
        gload_lds16(gb + aoff,            &sB[buf][(wid * 16) * 32]);
        gload_lds16(gb + aoff + 64LL * K, &sB[buf][(64 + wid * 16) * 32]);
    };

    f32x4 acc[4][4];
#pragma unroll
    for (int m = 0; m < 4; ++m)
#pragma unroll
        for (int n = 0; n < 4; ++n) acc[m][n] = (f32x4){0.f, 0.f, 0.f, 0.f};

    stage(0, 0);
    __syncthreads();

    const int wr = wid >> 1, wc = wid & 1;
    const int arow = wr * 64 + (lane & 15);
    const int brow = wc * 64 + (lane & 15);
    const int koff = (lane >> 4) * 8;

    for (int kt = 0; kt < kTiles; ++kt) {
        const int cur = kt & 1;
        if (kt + 1 < kTiles) stage(cur ^ 1, kt + 1);
        bf16x8 af[4], bfr[4];
#pragma unroll
        for (int m = 0; m < 4; ++m)
            af[m] = *(const bf16x8*)&sA[cur][(arow + m * 16) * 32 + koff];
#pragma unroll
        for (int n = 0; n < 4; ++n)
            bfr[n] = *(const bf16x8*)&sB[cur][(brow + n * 16) * 32 + koff];
#pragma unroll
        for (int m = 0; m < 4; ++m)
#pragma unroll
            for (int n = 0; n < 4; ++n)
                acc[m][n] = __builtin_amdgcn_mfma_f32_16x16x32_bf16(af[m], bfr[n], acc[m][n], 0, 0, 0);
        __syncthreads();
    }

    // C/D layout: col = lane&15, row = (lane>>4)*4 + r   [learn_hip m89]
    const int cr0 = bm * 128 + wr * 64 + (lane >> 4) * 4;
    const int cc0 = bn * 128 + wc * 64 + (lane & 15);
#pragma unroll
    for (int m = 0; m < 4; ++m) {
#pragma unroll
        for (int n = 0; n < 4; ++n) {
            const int col = cc0 + n * 16;
#pragma unroll
            for (int r = 0; r < 4; ++r) {
                const int row = cr0 + m * 16 + r;
                float v = acc[m][n][r];
                if (MODE == M_QKV) {
                    v += bias[col];
                    int hd = col / 192, rr = col % 192;
                    int b = row >> 10, s = row & 1023;
                    if (rr < 64)
                        qp[(long long)row * 768 + hd * 64 + rr] = (bf16)(v * 0.03608439182435161f);
                    else if (rr < 128)
                        kp[(long long)row * 768 + hd * 64 + (rr - 64)] = (bf16)v;
                    else
                        vp[((long long)b * 768 + hd * 64 + (rr - 128)) * 1024 + s] = (bf16)v;
                } else if (MODE == M_GELU) {
                    float xg = v + bias[col];
                    Cb[(long long)row * N + col] = (bf16)(xg / (1.f + __expf(-1.702f * xg)));
                } else if (MODE == M_RSPLIT) {
                    float add = v + (bz == 0 ? bias[col] : 0.f);
                    atomicAdd(&Cf[(long long)row * N + col], add);
                } else if (MODE == M_WM) {
                    Cb[(long long)bz * batchC + (long long)row * N + col] = (bf16)v;
                } else { // M_OUT (embed: fp32 + bias)
                    Cf[(long long)row * N + col] = v + bias[col];
                }
            }
        }
    }
}

// ---------------------------------------------------------------------------
// 64x128 tile GEMM, BK=32 (scores/PV causal granularity + final out).
// ---------------------------------------------------------------------------
template<int MODE>
__global__ __launch_bounds__(256)
void gemm64_k(const bf16* __restrict__ A, const bf16* __restrict__ B,
              int M, int N, int K,
              long long batchA, long long batchB, long long batchC,
              const float* __restrict__ bias,
              bf16* __restrict__ Cb, float* __restrict__ Cf)
{
    const int bm = blockIdx.x, bn = blockIdx.y, bz = blockIdx.z;
    if (MODE == M_SCORES && 2 * bn > bm) return;     // fully-masked tile
    int kTiles = K >> 5;
    if (MODE == M_PV) {                              // P[:,k]==0 for k>row
        int lim = 2 * bm + 2;
        if (lim < kTiles) kTiles = lim;
    }

    const int tid = threadIdx.x, wid = tid >> 6, lane = tid & 63;
    const bf16* Ab = A + (long long)bz * batchA + (long long)bm * 64 * K;
    const bf16* Bb = B + (long long)bz * batchB + (long long)bn * 128 * K;

    __shared__ __align__(16) bf16 sA[2][2048];
    __shared__ __align__(16) bf16 sB[2][4096];

    const int srow = wid * 16 + (lane >> 2);          // 0..63
    const int scol = (lane & 3) * 8;
    const long long aoff = (long long)srow * K + scol;

    auto stage = [&](int buf, int kt) {
        const bf16* ga = Ab + (long long)kt * 32;
        const bf16* gb = Bb + (long long)kt * 32;
        gload_lds16(ga + aoff,            &sA[buf][(wid * 16) * 32]);
        gload_lds16(gb + aoff,            &sB[buf][(wid * 16) * 32]);
        gload_lds16(gb + aoff + 64LL * K, &sB[buf][(64 + wid * 16) * 32]);
    };

    f32x4 acc[2][4];
#pragma unroll
    for (int m = 0; m < 2; ++m)
#pragma unroll
        for (int n = 0; n < 4; ++n) acc[m][n] = (f32x4){0.f, 0.f, 0.f, 0.f};

    stage(0, 0);
    __syncthreads();

    const int wr = wid >> 1, wc = wid & 1;
    const int arow = wr * 32 + (lane & 15);
    const int brow = wc * 64 + (lane & 15);
    const int koff = (lane >> 4) * 8;

    for (int kt = 0; kt < kTiles; ++kt) {
        const int cur = kt & 1;
        if (kt + 1 < kTiles) stage(cur ^ 1, kt + 1);
        bf16x8 af[2], bfr[4];
#pragma unroll
        for (int m = 0; m < 2; ++m)
            af[m] = *(const bf16x8*)&sA[cur][(arow + m * 16) * 32 + koff];
#pragma unroll
        for (int n = 0; n < 4; ++n)
            bfr[n] = *(const bf16x8*)&sB[cur][(brow + n * 16) * 32 + koff];
#pragma unroll
        for (int m = 0; m < 2; ++m)
#pragma unroll
            for (int n = 0; n < 4; ++n)
                acc[m][n] = __builtin_amdgcn_mfma_f32_16x16x32_bf16(af[m], bfr[n], acc[m][n], 0, 0, 0);
        __syncthreads();
    }

    const int cr0 = bm * 64 + wr * 32 + (lane >> 4) * 4;
    const int cc0 = bn * 128 + wc * 64 + (lane & 15);
#pragma unroll
    for (int m = 0; m < 2; ++m) {
#pragma unroll
        for (int n = 0; n < 4; ++n) {
            const int col = cc0 + n * 16;
#pragma unroll
            for (int r = 0; r < 4; ++r) {
                const int row = cr0 + m * 16 + r;
                float v = acc[m][n][r];
                if (MODE == M_SCORES || MODE == M_PV) {
                    Cb[(long long)bz * batchC + (long long)row * N + col] = (bf16)v;
                } else { // M_OUT (final projection, fp32 + bias)
                    Cf[(long long)row * N + col] = v + bias[col];
                }
            }
        }
    }
}

// ---------------------------------------------------------------------------
__global__ __launch_bounds__(256)
void cvt_bf16_k(const float* __restrict__ in, bf16* __restrict__ out, int n4)
{
    int i = blockIdx.x * 256 + threadIdx.x;
    if (i >= n4) return;
    float4 f = ((const float4*)in)[i];
    bf16x4 o = { (bf16)f.x, (bf16)f.y, (bf16)f.z, (bf16)f.w };
    ((bf16x4*)out)[i] = o;
}

// out[l][c][r] = (bf16) in[l][r][c]   (n x n per layer, n mult of 32)
__global__ __launch_bounds__(256)
void transpose_cvt_k(const float* __restrict__ in, bf16* __restrict__ out, int n)
{
    __shared__ float t[32][33];
    const int l = blockIdx.z;
    const int r0 = blockIdx.y * 32, c0 = blockIdx.x * 32;
    const float* src = in + (long long)l * n * n;
    bf16* dst = out + (long long)l * n * n;
    const int tx = threadIdx.x & 31, ty = threadIdx.x >> 5;   // 32x8
#pragma unroll
    for (int i = 0; i < 32; i += 8)
        t[ty + i][tx] = src[(long long)(r0 + ty + i) * n + c0 + tx];
    __syncthreads();
#pragma unroll
    for (int i = 0; i < 32; i += 8)
        dst[(long long)(c0 + ty + i) * n + r0 + tx] = (bf16)t[tx][ty + i];
}

// merged bias: bm[l][a] = sum_j o2w[l][a][j]*o1b[l][j] + o2b[l][a]; one wave per (l,a)
__global__ __launch_bounds__(256)
void bias_merge_k(const float* __restrict__ o2w, const float* __restrict__ o1b,
                  const float* __restrict__ o2b, float* __restrict__ bm, int total)
{
    const int wid = threadIdx.x >> 6, lane = threadIdx.x & 63;
    const int idx = blockIdx.x * 4 + wid;
    if (idx >= total) return;
    const int l = idx / 768, a = idx - l * 768;
    const float* wrow = o2w + ((long long)l * 768 + a) * 768;
    const float* brow = o1b + (long long)l * 768;
    float s = 0.f;
#pragma unroll
    for (int j = 0; j < 12; ++j) {
        int c = j * 64 + lane;
        s += wrow[c] * brow[c];
    }
#pragma unroll
    for (int o = 32; o; o >>= 1) s += __shfl_down(s, o);
    if (lane == 0) bm[idx] = s + o2b[(long long)l * 768 + a];
}

__global__ __launch_bounds__(256)
void cond_proj_k(const float* __restrict__ label, const float* __restrict__ sw,
                 const float* __restrict__ bw, float* __restrict__ scale,
                 float* __restrict__ bias, int total)
{
    int idx = blockIdx.x * 256 + threadIdx.x;
    if (idx >= total) return;
    int l = idx / 6144;
    int rem = idx - l * 6144;
    int b = rem / 768, d = rem - (rem / 768) * 768;
    const float* lab = label + b * 17;
    const float* swp = sw + ((long long)l * 768 + d) * 17;
    const float* bwp = bw + ((long long)l * 768 + d) * 17;
    float s = 0.f, bb = 0.f;
#pragma unroll
    for (int c = 0; c < 17; ++c) { float lv = lab[c]; s += lv * swp[c]; bb += lv * bwp[c]; }
    scale[idx] = s;
    bias[idx]  = bb;
}

// h[b,s,:] = (s==0 ? sos : xe[b,s-1,:]) + pos_bias(s)
__global__ __launch_bounds__(256)
void shift_pos_k(const float* __restrict__ xe, const float* __restrict__ sos,
                 const float* __restrict__ p0, const float* __restrict__ p1,
                 const float* __restrict__ p2, float* __restrict__ h)
{
    const int s = blockIdx.x, b = blockIdx.y;
    const int i0 = s >> 8, i1 = (s >> 4) & 15, i2 = s & 15;
    const float* xr = xe + ((long long)b * 1024 + (s - 1)) * 768;
#pragma unroll
    for (int j = 0; j < 3; ++j) {
        const int d = j * 256 + threadIdx.x;
        float v = (s == 0) ? sos[d] : xr[d];
        float pbv = (d < 256) ? p0[i0 * 256 + d]
                  : (d < 512) ? p1[i1 * 256 + (d - 256)]
                              : p2[i2 * 256 + (d - 512)];
        h[((long long)b * 1024 + s) * 768 + d] = v + pbv;
    }
}

__global__ __launch_bounds__(256)
void cond_ln_k(const float* __restrict__ h, const float* __restrict__ scale,
               const float* __restrict__ bias, bf16* __restrict__ out)
{
    const long long row = (long long)blockIdx.y * 1024 + blockIdx.x;
    const int b = blockIdx.y;
    const float* hr = h + row * 768;
    float v[3], sum = 0.f, sq = 0.f;
#pragma unroll
    for (int j = 0; j < 3; ++j) {
        v[j] = hr[j * 256 + threadIdx.x];
        sum += v[j]; sq += v[j] * v[j];
    }
    __shared__ float sm[8];
#pragma unroll
    for (int o = 32; o; o >>= 1) { sum += __shfl_down(sum, o); sq += __shfl_down(sq, o); }
    const int wid = threadIdx.x >> 6;
    if ((threadIdx.x & 63) == 0) { sm[wid] = sum; sm[4 + wid] = sq; }
    __syncthreads();
    sum = sm[0] + sm[1] + sm[2] + sm[3];
    sq  = sm[4] + sm[5] + sm[6] + sm[7];
    const float mean = sum * (1.f / 768.f);
    const float var  = sq * (1.f / 768.f) - mean * mean;
    const float rs   = rsqrtf(var + 1e-6f);
    const float* sc = scale + (long long)b * 768;
    const float* bi = bias  + (long long)b * 768;
    bf16* orow = out + row * 768;
#pragma unroll
    for (int j = 0; j < 3; ++j) {
        const int d = j * 256 + threadIdx.x;
        orow[d] = (bf16)((v[j] - mean) * rs * (1.f + sc[d]) + bi[d]);
    }
}

__global__ __launch_bounds__(256)
void softmax_k(bf16* __restrict__ P)
{
    const int i = blockIdx.x, b = blockIdx.y;
    bf16* row = P + ((long long)b * 1024 + i) * 1024;
    const int len = i + 1;
    float v[4], mx = -1e30f;
#pragma unroll
    for (int j = 0; j < 4; ++j) {
        int c = j * 256 + threadIdx.x;
        v[j] = (c < len) ? (float)row[c] : -1e30f;
        mx = fmaxf(mx, v[j]);
    }
    __shared__ float sm[8];
#pragma unroll
    for (int o = 32; o; o >>= 1) mx = fmaxf(mx, __shfl_down(mx, o));
    const int wid = threadIdx.x >> 6;
    if ((threadIdx.x & 63) == 0) sm[wid] = mx;
    __syncthreads();
    mx = fmaxf(fmaxf(sm[0], sm[1]), fmaxf(sm[2], sm[3]));
    float s = 0.f;
#pragma unroll
    for (int j = 0; j < 4; ++j) {
        v[j] = __expf(v[j] - mx);
        s += ((j * 256 + threadIdx.x) < len) ? v[j] : 0.f;
    }
#pragma unroll
    for (int o = 32; o; o >>= 1) s += __shfl_down(s, o);
    if ((threadIdx.x & 63) == 0) sm[4 + wid] = s;
    __syncthreads();
    s = sm[4] + sm[5] + sm[6] + sm[7];
    const float inv = 1.f / s;
#pragma unroll
    for (int j = 0; j < 4; ++j) {
        int c = j * 256 + threadIdx.x;
        row[c] = (c < len) ? (bf16)(v[j] * inv) : (bf16)0.f;
    }
}

__global__ __launch_bounds__(256)
void fill_k(float* o, int n, float v)
{
    int i = blockIdx.x * 256 + threadIdx.x;
    if (i < n) o[i] = v;
}

// ---------------------------------------------------------------------------
extern "C" void kernel_launch(void* const* d_in, const int* in_sizes, int n_in,
                              void* d_out, int out_size, void* d_ws, size_t ws_size,
                              hipStream_t stream)
{
    (void)in_sizes; (void)n_in;
    const float* x     = (const float*)d_in[0];
    const float* label = (const float*)d_in[2];
    const float* dw    = (const float*)d_in[3];
    const float* db    = (const float*)d_in[4];
    const float* sos   = (const float*)d_in[5];
    const float* p0    = (const float*)d_in[6];
    const float* p1    = (const float*)d_in[7];
    const float* p2    = (const float*)d_in[8];
    const float* ln1sw = (const float*)d_in[9];
    const float* ln1bw = (const float*)d_in[10];
    const float* qkvw  = (const float*)d_in[11];
    const float* qkvb  = (const float*)d_in[12];
    const float* ao1w  = (const float*)d_in[13];
    const float* ao1b  = (const float*)d_in[14];
    const float* ao2w  = (const float*)d_in[15];
    const float* ao2b  = (const float*)d_in[16];
    const float* ln2sw = (const float*)d_in[17];
    const float* ln2bw = (const float*)d_in[18];
    const float* m1w   = (const float*)d_in[19];
    const float* m1b   = (const float*)d_in[20];
    const float* m2w   = (const float*)d_in[21];
    const float* m2b   = (const float*)d_in[22];
    const float* lnfsw = (const float*)d_in[23];
    const float* lnfbw = (const float*)d_in[24];
    const float* outw  = (const float*)d_in[25];
    const float* outb  = (const float*)d_in[26];
    float* out = (float*)d_out;

    char* p = (char*)d_ws;
    auto alloc = [&](size_t bytes) { void* r = (void*)p; p += (bytes + 255) & ~(size_t)255; return r; };
    float* h    = (float*)alloc(8192LL * 768 * 4);
    bf16*  hn   = (bf16*) alloc(8192LL * 768 * 2);
    bf16*  q    = (bf16*) alloc(8192LL * 768 * 2);
    bf16*  kbuf = (bf16*) alloc(8192LL * 768 * 2);
    bf16*  vT   = (bf16*) alloc(8192LL * 768 * 2);   // [B,768,1024]
    bf16*  P    = (bf16*) alloc(8LL * 1024 * 1024 * 2);
    bf16*  attn = (bf16*) alloc(8192LL * 768 * 2);
    bf16*  mb   = (bf16*) alloc(8192LL * 3072 * 2);
    bf16*  wout = (bf16*) alloc(1024LL * 768 * 2);
    bf16*  wmA  = (bf16*) alloc(12LL * 768 * 768 * 2);   // merged o2@o1, bf16
    float* bmA  = (float*)alloc(12LL * 768 * 4);         // merged o-bias
    float* s1   = (float*)alloc(12LL * 8 * 768 * 4);
    float* b1   = (float*)alloc(12LL * 8 * 768 * 4);
    float* s2   = (float*)alloc(12LL * 8 * 768 * 4);
    float* b2   = (float*)alloc(12LL * 8 * 768 * 4);
    float* sf   = (float*)alloc(8LL * 768 * 4);
    float* bfb  = (float*)alloc(8LL * 768 * 4);

    size_t base_needed = (size_t)(p - (char*)d_ws);
    if (base_needed + 16LL * 1024 * 1024 > ws_size) {
        fill_k<<<(out_size + 255) / 256, 256, 0, stream>>>(out, out_size, 1e9f);
        return;
    }

    // weight conversion: all-layers-at-once if ws allows, else per-layer
    const long long SZ_QKV = 2304LL * 768, SZ_O = 768LL * 768, SZ_M = 3072LL * 768;
    size_t all_bytes = (size_t)(12 * (SZ_QKV + 2 * SZ_M)) * 2;
    bool allw = ((size_t)(p - (char*)d_ws) + all_bytes + 4096 <= ws_size);

    bf16 *wqkvA, *wm1A, *wm2A;
    if (allw) {
        wqkvA = (bf16*)alloc(12 * SZ_QKV * 2);
        wm1A  = (bf16*)alloc(12 * SZ_M * 2);
        wm2A  = (bf16*)alloc(12 * SZ_M * 2);
    } else {
        wqkvA = (bf16*)alloc(SZ_QKV * 2);
        wm1A  = (bf16*)alloc(SZ_M * 2);
        wm2A  = (bf16*)alloc(SZ_M * 2);
    }

    // one-time scratch aliased onto regions unused until the layer loop:
    //   P (16.8MB): xbf (1MB) | dwbf (0.1MB) | wo2bf (14.2MB, at elem 1048576)
    //   mb (50.3MB): xe (25.2MB) | o1t (14.2MB, at elem 12582912)
    bf16*  xbf   = (bf16*)P;
    bf16*  dwbf  = (bf16*)P + 524288;
    bf16*  wo2bf = (bf16*)P + 1048576;
    float* xe    = (float*)mb;
    bf16*  o1t   = mb + 12582912;

    // --- one-time precompute ---
    cvt_bf16_k<<<1024 * 768 / 4 / 256, 256, 0, stream>>>(outw, wout, 1024 * 768 / 4);
    cond_proj_k<<<(12 * 8 * 768 + 255) / 256, 256, 0, stream>>>(label, ln1sw, ln1bw, s1, b1, 12 * 8 * 768);
    cond_proj_k<<<(12 * 8 * 768 + 255) / 256, 256, 0, stream>>>(label, ln2sw, ln2bw, s2, b2, 12 * 8 * 768);
    cond_proj_k<<<(8 * 768 + 255) / 256, 256, 0, stream>>>(label, lnfsw, lnfbw, sf, bfb, 8 * 768);

    if (allw) {
        cvt_bf16_k<<<(int)(12 * SZ_QKV / 4 / 256), 256, 0, stream>>>(qkvw, wqkvA, (int)(12 * SZ_QKV / 4));
        cvt_bf16_k<<<(int)(12 * SZ_M / 4 / 256),   256, 0, stream>>>(m1w,  wm1A,  (int)(12 * SZ_M / 4));
        cvt_bf16_k<<<(int)(12 * SZ_M / 4 / 256),   256, 0, stream>>>(m2w,  wm2A,  (int)(12 * SZ_M / 4));
    }

    // merged out-proj: Wm[l] = o2[l] @ o1[l]  (bf16), bm[l] = o2[l]@o1b[l] + o2b[l]
    cvt_bf16_k<<<(int)(12 * SZ_O / 4 / 256), 256, 0, stream>>>(ao2w, wo2bf, (int)(12 * SZ_O / 4));
    transpose_cvt_k<<<dim3(24, 24, 12), 256, 0, stream>>>(ao1w, o1t, 768);
    gemm_k<M_WM><<<dim3(6, 6, 12), 256, 0, stream>>>(
        wo2bf, o1t, 768, 768, 768, SZ_O, SZ_O, SZ_O, 1,
        nullptr, wmA, nullptr, nullptr, nullptr, nullptr);
    bias_merge_k<<<(12 * 768 + 3) / 4, 256, 0, stream>>>(ao2w, ao1b, ao2b, bmA, 12 * 768);

    // embed: x->bf16, xe = x @ dw^T + db (fp32), then shift+pos
    cvt_bf16_k<<<8192 * 64 / 4 / 256, 256, 0, stream>>>(x, xbf, 8192 * 64 / 4);
    cvt_bf16_k<<<768 * 64 / 4 / 256, 256, 0, stream>>>(dw, dwbf, 768 * 64 / 4);
    gemm_k<M_OUT><<<dim3(64, 6, 1), 256, 0, stream>>>(
        xbf, dwbf, 8192, 768, 64, 0, 0, 0, 1, db, nullptr, xe, nullptr, nullptr, nullptr);
    shift_pos_k<<<dim3(1024, 8), 256, 0, stream>>>(xe, sos, p0, p1, p2, h);

    for (int l = 0; l < 12; ++l) {
        bf16 *wqkv, *wm1, *wm2;
        if (allw) {
            wqkv = wqkvA + (long long)l * SZ_QKV;
            wm1  = wm1A  + (long long)l * SZ_M;
            wm2  = wm2A  + (long long)l * SZ_M;
        } else {
            wqkv = wqkvA; wm1 = wm1A; wm2 = wm2A;
            cvt_bf16_k<<<(int)(SZ_QKV / 4 / 256), 256, 0, stream>>>(qkvw + (long long)l * SZ_QKV, wqkv, (int)(SZ_QKV / 4));
            cvt_bf16_k<<<(int)(SZ_M / 4 / 256),   256, 0, stream>>>(m1w  + (long long)l * SZ_M,   wm1,  (int)(SZ_M / 4));
            cvt_bf16_k<<<(int)(SZ_M / 4 / 256),   256, 0, stream>>>(m2w  + (long long)l * SZ_M,   wm2,  (int)(SZ_M / 4));
        }

        cond_ln_k<<<dim3(1024, 8), 256, 0, stream>>>(h, s1 + (long long)l * 6144, b1 + (long long)l * 6144, hn);

        gemm_k<M_QKV><<<dim3(64, 18, 1), 256, 0, stream>>>(
            hn, wqkv, 8192, 2304, 768, 0, 0, 0, 1,
            qkvb + (long long)l * 2304, nullptr, nullptr, q, kbuf, vT);

        gemm64_k<M_SCORES><<<dim3(16, 8, 8), 256, 0, stream>>>(
            q, kbuf, 1024, 1024, 768, 1024LL * 768, 1024LL * 768, 1024LL * 1024,
            nullptr, P, nullptr);

        softmax_k<<<dim3(1024, 8), 256, 0, stream>>>(P);

        gemm64_k<M_PV><<<dim3(16, 6, 8), 256, 0, stream>>>(
            P, vT, 1024, 768, 1024, 1024LL * 1024, 768LL * 1024, 1024LL * 768,
            nullptr, attn, nullptr);

        // merged out-proj, split-K=2, atomicAdd into residual h
        gemm_k<M_RSPLIT><<<dim3(64, 6, 2), 256, 0, stream>>>(
            attn, wmA + (long long)l * SZ_O, 8192, 768, 768, 0, 0, 0, 2,
            bmA + (long long)l * 768, nullptr, h, nullptr, nullptr, nullptr);

        cond_ln_k<<<dim3(1024, 8), 256, 0, stream>>>(h, s2 + (long long)l * 6144, b2 + (long long)l * 6144, hn);

        gemm_k<M_GELU><<<dim3(64, 24, 1), 256, 0, stream>>>(
            hn, wm1, 8192, 3072, 768, 0, 0, 0, 1,
            m1b + (long long)l * 3072, mb, nullptr, nullptr, nullptr, nullptr);

        // mlp2, split-K=4, atomicAdd into residual h
        gemm_k<M_RSPLIT><<<dim3(64, 6, 4), 256, 0, stream>>>(
            mb, wm2, 8192, 768, 3072, 0, 0, 0, 4,
            m2b + (long long)l * 768, nullptr, h, nullptr, nullptr, nullptr);
    }

    cond_ln_k<<<dim3(1024, 8), 256, 0, stream>>>(h, sf, bfb, hn);
    gemm64_k<M_OUT><<<dim3(128, 8, 1), 256, 0, stream>>>(
        hn, wout, 8192, 1024, 768, 0, 0, 0,
        outb, nullptr, out);
}

// Round 5
// 4505.641 us; speedup vs baseline: 1.0828x; 1.0828x over previous
//
#include <hip/hip_runtime.h>

typedef __bf16 bf16;
typedef __bf16 bf16x8 __attribute__((ext_vector_type(8)));
typedef __bf16 bf16x4 __attribute__((ext_vector_type(4)));
typedef float  f32x4  __attribute__((ext_vector_type(4)));

#define DEV __device__ __forceinline__

// async global->LDS, 16B per lane; lds dest must be wave-uniform base (HW adds lane*16)
DEV void gload_lds16(const bf16* g, bf16* l) {
    __builtin_amdgcn_global_load_lds(
        (__attribute__((address_space(1))) void*)g,
        (__attribute__((address_space(3))) void*)l, 16, 0, 0);
}

enum { M_QKV, M_SCORES, M_PV, M_RESID, M_GELU, M_OUT, M_WM };

// ---------------------------------------------------------------------------
// 128x128 tile m97-structure GEMM. C[m,n] = sum_k A[m,k]*B[n,k];
// A:[M,K], B:[N,K] bf16 row-major.
// M_RESID: Cf[row*N+col] += v + bias (single writer per element).
// M_WM:    blockIdx.z = batch index, bf16 out.
// ---------------------------------------------------------------------------
template<int MODE>
__global__ __launch_bounds__(256)
void gemm_k(const bf16* __restrict__ A, const bf16* __restrict__ B,
            int M, int N, int K,
            long long batchA, long long batchB, long long batchC,
            const float* __restrict__ bias,
            bf16* __restrict__ Cb, float* __restrict__ Cf,
            bf16* __restrict__ qp, bf16* __restrict__ kp, bf16* __restrict__ vp)
{
    const int bm = blockIdx.x, bn = blockIdx.y, bz = blockIdx.z;
    int kTiles = K >> 5;

    const int tid = threadIdx.x, wid = tid >> 6, lane = tid & 63;
    const bf16* Ab = A + (long long)bz * batchA + (long long)bm * 128 * K;
    const bf16* Bb = B + (long long)bz * batchB + (long long)bn * 128 * K;

    __shared__ __align__(16) bf16 sA[2][4096];
    __shared__ __align__(16) bf16 sB[2][4096];

    const int srow = wid * 16 + (lane >> 2);
    const int scol = (lane & 3) * 8;
    const long long aoff = (long long)srow * K + scol;

    auto stage = [&](int buf, int kt) {
        const bf16* ga = Ab + (long long)kt * 32;
        const bf16* gb = Bb + (long long)kt * 32;
        gload_lds16(ga + aoff,            &sA[buf][(wid * 16) * 32]);
        gload_lds16(ga + aoff + 64LL * K, &sA[buf][(64 + wid * 16) * 32]);
        gload_lds16(gb + aoff,            &sB[buf][(wid * 16) * 32]);
        gload_lds16(gb + aoff + 64LL * K, &sB[buf][(64 + wid * 16) * 32]);
    };

    f32x4 acc[4][4];
#pragma unroll
    for (int m = 0; m < 4; ++m)
#pragma unroll
        for (int n = 0; n < 4; ++n) acc[m][n] = (f32x4){0.f, 0.f, 0.f, 0.f};

    stage(0, 0);
    __syncthreads();

    const int wr = wid >> 1, wc = wid & 1;
    const int arow = wr * 64 + (lane & 15);
    const int brow = wc * 64 + (lane & 15);
    const int koff = (lane >> 4) * 8;

    for (int kt = 0; kt < kTiles; ++kt) {
        const int cur = kt & 1;
        if (kt + 1 < kTiles) stage(cur ^ 1, kt + 1);
        bf16x8 af[4], bfr[4];
#pragma unroll
        for (int m = 0; m < 4; ++m)
            af[m] = *(const bf16x8*)&sA[cur][(arow + m * 16) * 32 + koff];
#pragma unroll
        for (int n = 0; n < 4; ++n)
            bfr[n] = *(const bf16x8*)&sB[cur][(brow + n * 16) * 32 + koff];
#pragma unroll
        for (int m = 0; m < 4; ++m)
#pragma unroll
            for (int n = 0; n < 4; ++n)
                acc[m][n] = __builtin_amdgcn_mfma_f32_16x16x32_bf16(af[m], bfr[n], acc[m][n], 0, 0, 0);
        __syncthreads();
    }

    // C/D layout: col = lane&15, row = (lane>>4)*4 + r   [learn_hip m89]
    const int cr0 = bm * 128 + wr * 64 + (lane >> 4) * 4;
    const int cc0 = bn * 128 + wc * 64 + (lane & 15);
#pragma unroll
    for (int m = 0; m < 4; ++m) {
#pragma unroll
        for (int n = 0; n < 4; ++n) {
            const int col = cc0 + n * 16;
#pragma unroll
            for (int r = 0; r < 4; ++r) {
                const int row = cr0 + m * 16 + r;
                float v = acc[m][n][r];
                if (MODE == M_QKV) {
                    v += bias[col];
                    int hd = col / 192, rr = col % 192;
                    int b = row >> 10, s = row & 1023;
                    if (rr < 64)
                        qp[(long long)row * 768 + hd * 64 + rr] = (bf16)(v * 0.03608439182435161f);
                    else if (rr < 128)
                        kp[(long long)row * 768 + hd * 64 + (rr - 64)] = (bf16)v;
                    else
                        vp[((long long)b * 768 + hd * 64 + (rr - 128)) * 1024 + s] = (bf16)v;
                } else if (MODE == M_GELU) {
                    float xg = v + bias[col];
                    Cb[(long long)row * N + col] = (bf16)(xg / (1.f + __expf(-1.702f * xg)));
                } else if (MODE == M_RESID) {
                    long long idx = (long long)row * N + col;
                    Cf[idx] += v + bias[col];
                } else if (MODE == M_WM) {
                    Cb[(long long)bz * batchC + (long long)row * N + col] = (bf16)v;
                } else { // M_OUT (fp32 + bias)
                    Cf[(long long)row * N + col] = v + bias[col];
                }
            }
        }
    }
}

// ---------------------------------------------------------------------------
// 64x128 tile GEMM, BK=32 (scores/PV causal granularity + final out).
// ---------------------------------------------------------------------------
template<int MODE>
__global__ __launch_bounds__(256)
void gemm64_k(const bf16* __restrict__ A, const bf16* __restrict__ B,
              int M, int N, int K,
              long long batchA, long long batchB, long long batchC,
              const float* __restrict__ bias,
              bf16* __restrict__ Cb, float* __restrict__ Cf)
{
    const int bm = blockIdx.x, bn = blockIdx.y, bz = blockIdx.z;
    if (MODE == M_SCORES && 2 * bn > bm) return;     // fully-masked tile
    int kTiles = K >> 5;
    if (MODE == M_PV) {                              // P[:,k]==0 for k>row
        int lim = 2 * bm + 2;
        if (lim < kTiles) kTiles = lim;
    }

    const int tid = threadIdx.x, wid = tid >> 6, lane = tid & 63;
    const bf16* Ab = A + (long long)bz * batchA + (long long)bm * 64 * K;
    const bf16* Bb = B + (long long)bz * batchB + (long long)bn * 128 * K;

    __shared__ __align__(16) bf16 sA[2][2048];
    __shared__ __align__(16) bf16 sB[2][4096];

    const int srow = wid * 16 + (lane >> 2);          // 0..63
    const int scol = (lane & 3) * 8;
    const long long aoff = (long long)srow * K + scol;

    auto stage = [&](int buf, int kt) {
        const bf16* ga = Ab + (long long)kt * 32;
        const bf16* gb = Bb + (long long)kt * 32;
        gload_lds16(ga + aoff,            &sA[buf][(wid * 16) * 32]);
        gload_lds16(gb + aoff,            &sB[buf][(wid * 16) * 32]);
        gload_lds16(gb + aoff + 64LL * K, &sB[buf][(64 + wid * 16) * 32]);
    };

    f32x4 acc[2][4];
#pragma unroll
    for (int m = 0; m < 2; ++m)
#pragma unroll
        for (int n = 0; n < 4; ++n) acc[m][n] = (f32x4){0.f, 0.f, 0.f, 0.f};

    stage(0, 0);
    __syncthreads();

    const int wr = wid >> 1, wc = wid & 1;
    const int arow = wr * 32 + (lane & 15);
    const int brow = wc * 64 + (lane & 15);
    const int koff = (lane >> 4) * 8;

    for (int kt = 0; kt < kTiles; ++kt) {
        const int cur = kt & 1;
        if (kt + 1 < kTiles) stage(cur ^ 1, kt + 1);
        bf16x8 af[2], bfr[4];
#pragma unroll
        for (int m = 0; m < 2; ++m)
            af[m] = *(const bf16x8*)&sA[cur][(arow + m * 16) * 32 + koff];
#pragma unroll
        for (int n = 0; n < 4; ++n)
            bfr[n] = *(const bf16x8*)&sB[cur][(brow + n * 16) * 32 + koff];
#pragma unroll
        for (int m = 0; m < 2; ++m)
#pragma unroll
            for (int n = 0; n < 4; ++n)
                acc[m][n] = __builtin_amdgcn_mfma_f32_16x16x32_bf16(af[m], bfr[n], acc[m][n], 0, 0, 0);
        __syncthreads();
    }

    const int cr0 = bm * 64 + wr * 32 + (lane >> 4) * 4;
    const int cc0 = bn * 128 + wc * 64 + (lane & 15);
#pragma unroll
    for (int m = 0; m < 2; ++m) {
#pragma unroll
        for (int n = 0; n < 4; ++n) {
            const int col = cc0 + n * 16;
#pragma unroll
            for (int r = 0; r < 4; ++r) {
                const int row = cr0 + m * 16 + r;
                float v = acc[m][n][r];
                if (MODE == M_SCORES || MODE == M_PV) {
                    Cb[(long long)bz * batchC + (long long)row * N + col] = (bf16)v;
                } else { // M_OUT (final projection, fp32 + bias)
                    Cf[(long long)row * N + col] = v + bias[col];
                }
            }
        }
    }
}

// ---------------------------------------------------------------------------
__global__ __launch_bounds__(256)
void cvt_bf16_k(const float* __restrict__ in, bf16* __restrict__ out, int n4)
{
    int i = blockIdx.x * 256 + threadIdx.x;
    if (i >= n4) return;
    float4 f = ((const float4*)in)[i];
    bf16x4 o = { (bf16)f.x, (bf16)f.y, (bf16)f.z, (bf16)f.w };
    ((bf16x4*)out)[i] = o;
}

// out[l][c][r] = (bf16) in[l][r][c]   (n x n per layer, n mult of 32)
__global__ __launch_bounds__(256)
void transpose_cvt_k(const float* __restrict__ in, bf16* __restrict__ out, int n)
{
    __shared__ float t[32][33];
    const int l = blockIdx.z;
    const int r0 = blockIdx.y * 32, c0 = blockIdx.x * 32;
    const float* src = in + (long long)l * n * n;
    bf16* dst = out + (long long)l * n * n;
    const int tx = threadIdx.x & 31, ty = threadIdx.x >> 5;   // 32x8
#pragma unroll
    for (int i = 0; i < 32; i += 8)
        t[ty + i][tx] = src[(long long)(r0 + ty + i) * n + c0 + tx];
    __syncthreads();
#pragma unroll
    for (int i = 0; i < 32; i += 8)
        dst[(long long)(c0 + ty + i) * n + r0 + tx] = (bf16)t[tx][ty + i];
}

// merged bias: bm[l][a] = sum_j o2w[l][a][j]*o1b[l][j] + o2b[l][a]; one wave per (l,a)
__global__ __launch_bounds__(256)
void bias_merge_k(const float* __restrict__ o2w, const float* __restrict__ o1b,
                  const float* __restrict__ o2b, float* __restrict__ bm, int total)
{
    const int wid = threadIdx.x >> 6, lane = threadIdx.x & 63;
    const int idx = blockIdx.x * 4 + wid;
    if (idx >= total) return;
    const int l = idx / 768, a = idx - l * 768;
    const float* wrow = o2w + ((long long)l * 768 + a) * 768;
    const float* brow = o1b + (long long)l * 768;
    float s = 0.f;
#pragma unroll
    for (int j = 0; j < 12; ++j) {
        int c = j * 64 + lane;
        s += wrow[c] * brow[c];
    }
#pragma unroll
    for (int o = 32; o; o >>= 1) s += __shfl_down(s, o);
    if (lane == 0) bm[idx] = s + o2b[(long long)l * 768 + a];
}

__global__ __launch_bounds__(256)
void cond_proj_k(const float* __restrict__ label, const float* __restrict__ sw,
                 const float* __restrict__ bw, float* __restrict__ scale,
                 float* __restrict__ bias, int total)
{
    int idx = blockIdx.x * 256 + threadIdx.x;
    if (idx >= total) return;
    int l = idx / 6144;
    int rem = idx - l * 6144;
    int b = rem / 768, d = rem - (rem / 768) * 768;
    const float* lab = label + b * 17;
    const float* swp = sw + ((long long)l * 768 + d) * 17;
    const float* bwp = bw + ((long long)l * 768 + d) * 17;
    float s = 0.f, bb = 0.f;
#pragma unroll
    for (int c = 0; c < 17; ++c) { float lv = lab[c]; s += lv * swp[c]; bb += lv * bwp[c]; }
    scale[idx] = s;
    bias[idx]  = bb;
}

// h[b,s,:] = (s==0 ? sos : xe[b,s-1,:]) + pos_bias(s)
__global__ __launch_bounds__(256)
void shift_pos_k(const float* __restrict__ xe, const float* __restrict__ sos,
                 const float* __restrict__ p0, const float* __restrict__ p1,
                 const float* __restrict__ p2, float* __restrict__ h)
{
    const int s = blockIdx.x, b = blockIdx.y;
    const int i0 = s >> 8, i1 = (s >> 4) & 15, i2 = s & 15;
    const float* xr = xe + ((long long)b * 1024 + (s - 1)) * 768;
#pragma unroll
    for (int j = 0; j < 3; ++j) {
        const int d = j * 256 + threadIdx.x;
        float v = (s == 0) ? sos[d] : xr[d];
        float pbv = (d < 256) ? p0[i0 * 256 + d]
                  : (d < 512) ? p1[i1 * 256 + (d - 256)]
                              : p2[i2 * 256 + (d - 512)];
        h[((long long)b * 1024 + s) * 768 + d] = v + pbv;
    }
}

__global__ __launch_bounds__(256)
void cond_ln_k(const float* __restrict__ h, const float* __restrict__ scale,
               const float* __restrict__ bias, bf16* __restrict__ out)
{
    const long long row = (long long)blockIdx.y * 1024 + blockIdx.x;
    const int b = blockIdx.y;
    const float* hr = h + row * 768;
    float v[3], sum = 0.f, sq = 0.f;
#pragma unroll
    for (int j = 0; j < 3; ++j) {
        v[j] = hr[j * 256 + threadIdx.x];
        sum += v[j]; sq += v[j] * v[j];
    }
    __shared__ float sm[8];
#pragma unroll
    for (int o = 32; o; o >>= 1) { sum += __shfl_down(sum, o); sq += __shfl_down(sq, o); }
    const int wid = threadIdx.x >> 6;
    if ((threadIdx.x & 63) == 0) { sm[wid] = sum; sm[4 + wid] = sq; }
    __syncthreads();
    sum = sm[0] + sm[1] + sm[2] + sm[3];
    sq  = sm[4] + sm[5] + sm[6] + sm[7];
    const float mean = sum * (1.f / 768.f);
    const float var  = sq * (1.f / 768.f) - mean * mean;
    const float rs   = rsqrtf(var + 1e-6f);
    const float* sc = scale + (long long)b * 768;
    const float* bi = bias  + (long long)b * 768;
    bf16* orow = out + row * 768;
#pragma unroll
    for (int j = 0; j < 3; ++j) {
        const int d = j * 256 + threadIdx.x;
        orow[d] = (bf16)((v[j] - mean) * rs * (1.f + sc[d]) + bi[d]);
    }
}

// causal softmax over row i. Reads/writes only cols < ceil64(i+1): PV's
// truncated K-loop never touches cols beyond that boundary, and M_SCORES
// skips those tiles entirely, so the strictly-upper region stays untouched.
__global__ __launch_bounds__(256)
void softmax_k(bf16* __restrict__ P)
{
    const int i = blockIdx.x, b = blockIdx.y;
    bf16* row = P + ((long long)b * 1024 + i) * 1024;
    const int len = i + 1;
    const int lim = (i | 63) + 1;          // 64-col boundary PV can read up to
    float v[4], mx = -1e30f;
#pragma unroll
    for (int j = 0; j < 4; ++j) {
        int c = j * 256 + threadIdx.x;
        v[j] = (c < len) ? (float)row[c] : -1e30f;
        mx = fmaxf(mx, v[j]);
    }
    __shared__ float sm[8];
#pragma unroll
    for (int o = 32; o; o >>= 1) mx = fmaxf(mx, __shfl_down(mx, o));
    const int wid = threadIdx.x >> 6;
    if ((threadIdx.x & 63) == 0) sm[wid] = mx;
    __syncthreads();
    mx = fmaxf(fmaxf(sm[0], sm[1]), fmaxf(sm[2], sm[3]));
    float s = 0.f;
#pragma unroll
    for (int j = 0; j < 4; ++j) {
        v[j] = __expf(v[j] - mx);
        s += ((j * 256 + threadIdx.x) < len) ? v[j] : 0.f;
    }
#pragma unroll
    for (int o = 32; o; o >>= 1) s += __shfl_down(s, o);
    if ((threadIdx.x & 63) == 0) sm[4 + wid] = s;
    __syncthreads();
    s = sm[4] + sm[5] + sm[6] + sm[7];
    const float inv = 1.f / s;
#pragma unroll
    for (int j = 0; j < 4; ++j) {
        int c = j * 256 + threadIdx.x;
        if (c < lim) row[c] = (c < len) ? (bf16)(v[j] * inv) : (bf16)0.f;
    }
}

__global__ __launch_bounds__(256)
void fill_k(float* o, int n, float v)
{
    int i = blockIdx.x * 256 + threadIdx.x;
    if (i < n) o[i] = v;
}

// ---------------------------------------------------------------------------
extern "C" void kernel_launch(void* const* d_in, const int* in_sizes, int n_in,
                              void* d_out, int out_size, void* d_ws, size_t ws_size,
                              hipStream_t stream)
{
    (void)in_sizes; (void)n_in;
    const float* x     = (const float*)d_in[0];
    const float* label = (const float*)d_in[2];
    const float* dw    = (const float*)d_in[3];
    const float* db    = (const float*)d_in[4];
    const float* sos   = (const float*)d_in[5];
    const float* p0    = (const float*)d_in[6];
    const float* p1    = (const float*)d_in[7];
    const float* p2    = (const float*)d_in[8];
    const float* ln1sw = (const float*)d_in[9];
    const float* ln1bw = (const float*)d_in[10];
    const float* qkvw  = (const float*)d_in[11];
    const float* qkvb  = (const float*)d_in[12];
    const float* ao1w  = (const float*)d_in[13];
    const float* ao1b  = (const float*)d_in[14];
    const float* ao2w  = (const float*)d_in[15];
    const float* ao2b  = (const float*)d_in[16];
    const float* ln2sw = (const float*)d_in[17];
    const float* ln2bw = (const float*)d_in[18];
    const float* m1w   = (const float*)d_in[19];
    const float* m1b   = (const float*)d_in[20];
    const float* m2w   = (const float*)d_in[21];
    const float* m2b   = (const float*)d_in[22];
    const float* lnfsw = (const float*)d_in[23];
    const float* lnfbw = (const float*)d_in[24];
    const float* outw  = (const float*)d_in[25];
    const float* outb  = (const float*)d_in[26];
    float* out = (float*)d_out;

    char* p = (char*)d_ws;
    auto alloc = [&](size_t bytes) { void* r = (void*)p; p += (bytes + 255) & ~(size_t)255; return r; };
    float* h    = (float*)alloc(8192LL * 768 * 4);
    bf16*  hn   = (bf16*) alloc(8192LL * 768 * 2);
    bf16*  q    = (bf16*) alloc(8192LL * 768 * 2);
    bf16*  kbuf = (bf16*) alloc(8192LL * 768 * 2);
    bf16*  vT   = (bf16*) alloc(8192LL * 768 * 2);   // [B,768,1024]
    bf16*  P    = (bf16*) alloc(8LL * 1024 * 1024 * 2);
    bf16*  attn = (bf16*) alloc(8192LL * 768 * 2);
    bf16*  mb   = (bf16*) alloc(8192LL * 3072 * 2);
    bf16*  wout = (bf16*) alloc(1024LL * 768 * 2);
    bf16*  wmA  = (bf16*) alloc(12LL * 768 * 768 * 2);   // merged o2@o1, bf16
    float* bmA  = (float*)alloc(12LL * 768 * 4);         // merged o-bias
    float* s1   = (float*)alloc(12LL * 8 * 768 * 4);
    float* b1   = (float*)alloc(12LL * 8 * 768 * 4);
    float* s2   = (float*)alloc(12LL * 8 * 768 * 4);
    float* b2   = (float*)alloc(12LL * 8 * 768 * 4);
    float* sf   = (float*)alloc(8LL * 768 * 4);
    float* bfb  = (float*)alloc(8LL * 768 * 4);

    size_t base_needed = (size_t)(p - (char*)d_ws);
    if (base_needed + 16LL * 1024 * 1024 > ws_size) {
        fill_k<<<(out_size + 255) / 256, 256, 0, stream>>>(out, out_size, 1e9f);
        return;
    }

    // weight conversion: all-layers-at-once if ws allows, else per-layer
    const long long SZ_QKV = 2304LL * 768, SZ_O = 768LL * 768, SZ_M = 3072LL * 768;
    size_t all_bytes = (size_t)(12 * (SZ_QKV + 2 * SZ_M)) * 2;
    bool allw = ((size_t)(p - (char*)d_ws) + all_bytes + 4096 <= ws_size);

    bf16 *wqkvA, *wm1A, *wm2A;
    if (allw) {
        wqkvA = (bf16*)alloc(12 * SZ_QKV * 2);
        wm1A  = (bf16*)alloc(12 * SZ_M * 2);
        wm2A  = (bf16*)alloc(12 * SZ_M * 2);
    } else {
        wqkvA = (bf16*)alloc(SZ_QKV * 2);
        wm1A  = (bf16*)alloc(SZ_M * 2);
        wm2A  = (bf16*)alloc(SZ_M * 2);
    }

    // one-time scratch aliased onto regions unused until the layer loop:
    //   P (16.8MB): xbf (1MB) | dwbf (0.1MB) | wo2bf (14.2MB, at elem 1048576)
    //   mb (50.3MB): xe (25.2MB) | o1t (14.2MB, at elem 12582912)
    bf16*  xbf   = (bf16*)P;
    bf16*  dwbf  = (bf16*)P + 524288;
    bf16*  wo2bf = (bf16*)P + 1048576;
    float* xe    = (float*)mb;
    bf16*  o1t   = mb + 12582912;

    // --- one-time precompute ---
    cvt_bf16_k<<<1024 * 768 / 4 / 256, 256, 0, stream>>>(outw, wout, 1024 * 768 / 4);
    cond_proj_k<<<(12 * 8 * 768 + 255) / 256, 256, 0, stream>>>(label, ln1sw, ln1bw, s1, b1, 12 * 8 * 768);
    cond_proj_k<<<(12 * 8 * 768 + 255) / 256, 256, 0, stream>>>(label, ln2sw, ln2bw, s2, b2, 12 * 8 * 768);
    cond_proj_k<<<(8 * 768 + 255) / 256, 256, 0, stream>>>(label, lnfsw, lnfbw, sf, bfb, 8 * 768);

    if (allw) {
        cvt_bf16_k<<<(int)(12 * SZ_QKV / 4 / 256), 256, 0, stream>>>(qkvw, wqkvA, (int)(12 * SZ_QKV / 4));
        cvt_bf16_k<<<(int)(12 * SZ_M / 4 / 256),   256, 0, stream>>>(m1w,  wm1A,  (int)(12 * SZ_M / 4));
        cvt_bf16_k<<<(int)(12 * SZ_M / 4 / 256),   256, 0, stream>>>(m2w,  wm2A,  (int)(12 * SZ_M / 4));
    }

    // merged out-proj: Wm[l] = o2[l] @ o1[l]  (bf16), bm[l] = o2[l]@o1b[l] + o2b[l]
    cvt_bf16_k<<<(int)(12 * SZ_O / 4 / 256), 256, 0, stream>>>(ao2w, wo2bf, (int)(12 * SZ_O / 4));
    transpose_cvt_k<<<dim3(24, 24, 12), 256, 0, stream>>>(ao1w, o1t, 768);
    gemm_k<M_WM><<<dim3(6, 6, 12), 256, 0, stream>>>(
        wo2bf, o1t, 768, 768, 768, SZ_O, SZ_O, SZ_O,
        nullptr, wmA, nullptr, nullptr, nullptr, nullptr);
    bias_merge_k<<<(12 * 768 + 3) / 4, 256, 0, stream>>>(ao2w, ao1b, ao2b, bmA, 12 * 768);

    // embed: x->bf16, xe = x @ dw^T + db (fp32), then shift+pos
    cvt_bf16_k<<<8192 * 64 / 4 / 256, 256, 0, stream>>>(x, xbf, 8192 * 64 / 4);
    cvt_bf16_k<<<768 * 64 / 4 / 256, 256, 0, stream>>>(dw, dwbf, 768 * 64 / 4);
    gemm_k<M_OUT><<<dim3(64, 6, 1), 256, 0, stream>>>(
        xbf, dwbf, 8192, 768, 64, 0, 0, 0, db, nullptr, xe, nullptr, nullptr, nullptr);
    shift_pos_k<<<dim3(1024, 8), 256, 0, stream>>>(xe, sos, p0, p1, p2, h);

    for (int l = 0; l < 12; ++l) {
        bf16 *wqkv, *wm1, *wm2;
        if (allw) {
            wqkv = wqkvA + (long long)l * SZ_QKV;
            wm1  = wm1A  + (long long)l * SZ_M;
            wm2  = wm2A  + (long long)l * SZ_M;
        } else {
            wqkv = wqkvA; wm1 = wm1A; wm2 = wm2A;
            cvt_bf16_k<<<(int)(SZ_QKV / 4 / 256), 256, 0, stream>>>(qkvw + (long long)l * SZ_QKV, wqkv, (int)(SZ_QKV / 4));
            cvt_bf16_k<<<(int)(SZ_M / 4 / 256),   256, 0, stream>>>(m1w  + (long long)l * SZ_M,   wm1,  (int)(SZ_M / 4));
            cvt_bf16_k<<<(int)(SZ_M / 4 / 256),   256, 0, stream>>>(m2w  + (long long)l * SZ_M,   wm2,  (int)(SZ_M / 4));
        }

        cond_ln_k<<<dim3(1024, 8), 256, 0, stream>>>(h, s1 + (long long)l * 6144, b1 + (long long)l * 6144, hn);

        gemm_k<M_QKV><<<dim3(64, 18, 1), 256, 0, stream>>>(
            hn, wqkv, 8192, 2304, 768, 0, 0, 0,
            qkvb + (long long)l * 2304, nullptr, nullptr, q, kbuf, vT);

        gemm64_k<M_SCORES><<<dim3(16, 8, 8), 256, 0, stream>>>(
            q, kbuf, 1024, 1024, 768, 1024LL * 768, 1024LL * 768, 1024LL * 1024,
            nullptr, P, nullptr);

        softmax_k<<<dim3(1024, 8), 256, 0, stream>>>(P);

        gemm64_k<M_PV><<<dim3(16, 6, 8), 256, 0, stream>>>(
            P, vT, 1024, 768, 1024, 1024LL * 1024, 768LL * 1024, 1024LL * 768,
            nullptr, attn, nullptr);

        // merged out-proj (o2@o1 fused), residual add into h
        gemm_k<M_RESID><<<dim3(64, 6, 1), 256, 0, stream>>>(
            attn, wmA + (long long)l * SZ_O, 8192, 768, 768, 0, 0, 0,
            bmA + (long long)l * 768, nullptr, h, nullptr, nullptr, nullptr);

        cond_ln_k<<<dim3(1024, 8), 256, 0, stream>>>(h, s2 + (long long)l * 6144, b2 + (long long)l * 6144, hn);

        gemm_k<M_GELU><<<dim3(64, 24, 1), 256, 0, stream>>>(
            hn, wm1, 8192, 3072, 768, 0, 0, 0,
            m1b + (long long)l * 3072, mb, nullptr, nullptr, nullptr, nullptr);

        gemm_k<M_RESID><<<dim3(64, 6, 1), 256, 0, stream>>>(
            mb, wm2, 8192, 768, 3072, 0, 0, 0,
            m2b + (long long)l * 768, nullptr, h, nullptr, nullptr, nullptr);
    }

    cond_ln_k<<<dim3(1024, 8), 256, 0, stream>>>(h, sf, bfb, hn);
    gemm64_k<M_OUT><<<dim3(128, 8, 1), 256, 0, stream>>>(
        hn, wout, 8192, 1024, 768, 0, 0, 0,
        outb, nullptr, out);
}

// Round 6
// 3980.043 us; speedup vs baseline: 1.2258x; 1.1321x over previous
//
#include <hip/hip_runtime.h>

typedef __bf16 bf16;
typedef __bf16 bf16x8 __attribute__((ext_vector_type(8)));
typedef __bf16 bf16x4 __attribute__((ext_vector_type(4)));
typedef float  f32x4  __attribute__((ext_vector_type(4)));

#define DEV __device__ __forceinline__

// async global->LDS, 16B per lane; lds dest must be wave-uniform base (HW adds lane*16)
DEV void gload_lds16(const bf16* g, bf16* l) {
    __builtin_amdgcn_global_load_lds(
        (__attribute__((address_space(1))) void*)g,
        (__attribute__((address_space(3))) void*)l, 16, 0, 0);
}

DEV void barrier_raw() {
    asm volatile("" ::: "memory");
    __builtin_amdgcn_s_barrier();
    asm volatile("" ::: "memory");
}

enum { M_QKV, M_SCORES, M_PV, M_RESID, M_GELU, M_OUT, M_WM };

// ---------------------------------------------------------------------------
// 128x128 tile GEMM, 4-buffer 3-ahead counted-vmcnt pipeline (T4).
// C[m,n] = sum_k A[m,k]*B[n,k]; A:[M,K], B:[N,K] bf16 row-major.
// LDS: 4 x (8KB A + 8KB B) = 64KB dynamic.
// ---------------------------------------------------------------------------
template<int MODE>
__global__ __launch_bounds__(256)
void gemm_k(const bf16* __restrict__ A, const bf16* __restrict__ B,
            int M, int N, int K,
            long long batchA, long long batchB, long long batchC,
            const float* __restrict__ bias,
            bf16* __restrict__ Cb, float* __restrict__ Cf,
            bf16* __restrict__ qp, bf16* __restrict__ kp, bf16* __restrict__ vp)
{
    const int bm = blockIdx.x, bn = blockIdx.y, bz = blockIdx.z;
    const int kTiles = K >> 5;

    const int tid = threadIdx.x, wid = tid >> 6, lane = tid & 63;
    const bf16* Ab = A + (long long)bz * batchA + (long long)bm * 128 * K;
    const bf16* Bb = B + (long long)bz * batchB + (long long)bn * 128 * K;

    extern __shared__ __align__(16) bf16 smem[];   // 32768 elems = 64KB
    bf16* sA = smem;            // [4][4096]
    bf16* sB = smem + 16384;    // [4][4096]

    const int srow = wid * 16 + (lane >> 2);
    const int scol = (lane & 3) * 8;
    const long long aoff = (long long)srow * K + scol;

    auto stage = [&](int buf, int kt) {
        const bf16* ga = Ab + (long long)kt * 32;
        const bf16* gb = Bb + (long long)kt * 32;
        bf16* a = sA + buf * 4096;
        bf16* b = sB + buf * 4096;
        gload_lds16(ga + aoff,            a + (wid * 16) * 32);
        gload_lds16(ga + aoff + 64LL * K, a + (64 + wid * 16) * 32);
        gload_lds16(gb + aoff,            b + (wid * 16) * 32);
        gload_lds16(gb + aoff + 64LL * K, b + (64 + wid * 16) * 32);
    };

    f32x4 acc[4][4];
#pragma unroll
    for (int m = 0; m < 4; ++m)
#pragma unroll
        for (int n = 0; n < 4; ++n) acc[m][n] = (f32x4){0.f, 0.f, 0.f, 0.f};

    const int npre = kTiles < 3 ? kTiles : 3;
    for (int t = 0; t < npre; ++t) stage(t, t);

    const int wr = wid >> 1, wc = wid & 1;
    const int arow = wr * 64 + (lane & 15);
    const int brow = wc * 64 + (lane & 15);
    const int koff = (lane >> 4) * 8;

    for (int kt = 0; kt < kTiles; ++kt) {
        const int rem = kTiles - 1 - kt;
        if (rem >= 2)      asm volatile("s_waitcnt vmcnt(8)" ::: "memory");
        else if (rem == 1) asm volatile("s_waitcnt vmcnt(4)" ::: "memory");
        else               asm volatile("s_waitcnt vmcnt(0)" ::: "memory");
        barrier_raw();   // all waves: stage(kt) visible; prev-iter reads done
        if (kt + 3 < kTiles) stage((kt + 3) & 3, kt + 3);

        const int cur = kt & 3;
        const bf16* a = sA + cur * 4096;
        const bf16* b = sB + cur * 4096;
        bf16x8 af[4], bfr[4];
#pragma unroll
        for (int m = 0; m < 4; ++m)
            af[m] = *(const bf16x8*)&a[(arow + m * 16) * 32 + koff];
#pragma unroll
        for (int n = 0; n < 4; ++n)
            bfr[n] = *(const bf16x8*)&b[(brow + n * 16) * 32 + koff];
#pragma unroll
        for (int m = 0; m < 4; ++m)
#pragma unroll
            for (int n = 0; n < 4; ++n)
                acc[m][n] = __builtin_amdgcn_mfma_f32_16x16x32_bf16(af[m], bfr[n], acc[m][n], 0, 0, 0);
    }

    // C/D layout: col = lane&15, row = (lane>>4)*4 + r   [learn_hip m89]
    const int cr0 = bm * 128 + wr * 64 + (lane >> 4) * 4;
    const int cc0 = bn * 128 + wc * 64 + (lane & 15);
#pragma unroll
    for (int m = 0; m < 4; ++m) {
#pragma unroll
        for (int n = 0; n < 4; ++n) {
            const int col = cc0 + n * 16;
#pragma unroll
            for (int r = 0; r < 4; ++r) {
                const int row = cr0 + m * 16 + r;
                float v = acc[m][n][r];
                if (MODE == M_QKV) {
                    v += bias[col];
                    int hd = col / 192, rr = col % 192;
                    int b2 = row >> 10, s = row & 1023;
                    if (rr < 64)
                        qp[(long long)row * 768 + hd * 64 + rr] = (bf16)(v * 0.03608439182435161f);
                    else if (rr < 128)
                        kp[(long long)row * 768 + hd * 64 + (rr - 64)] = (bf16)v;
                    else
                        vp[((long long)b2 * 768 + hd * 64 + (rr - 128)) * 1024 + s] = (bf16)v;
                } else if (MODE == M_GELU) {
                    float xg = v + bias[col];
                    Cb[(long long)row * N + col] = (bf16)(xg / (1.f + __expf(-1.702f * xg)));
                } else if (MODE == M_RESID) {
                    long long idx = (long long)row * N + col;
                    Cf[idx] += v + bias[col];
                } else if (MODE == M_WM) {
                    Cb[(long long)bz * batchC + (long long)row * N + col] = (bf16)v;
                } else { // M_OUT (fp32 + bias)
                    Cf[(long long)row * N + col] = v + bias[col];
                }
            }
        }
    }
}

// ---------------------------------------------------------------------------
// 64x128 tile GEMM, same 4-buffer counted-vmcnt pipeline (3 gloads/stage).
// For scores/PV (causal granularity) + final out. LDS 48KB dynamic.
// ---------------------------------------------------------------------------
template<int MODE>
__global__ __launch_bounds__(256)
void gemm64_k(const bf16* __restrict__ A, const bf16* __restrict__ B,
              int M, int N, int K,
              long long batchA, long long batchB, long long batchC,
              const float* __restrict__ bias,
              bf16* __restrict__ Cb, float* __restrict__ Cf)
{
    const int bm = blockIdx.x, bn = blockIdx.y, bz = blockIdx.z;
    if (MODE == M_SCORES && 2 * bn > bm) return;     // fully-masked tile
    int kTiles = K >> 5;
    if (MODE == M_PV) {                              // P[:,k]==0 for k>row
        int lim = 2 * bm + 2;
        if (lim < kTiles) kTiles = lim;
    }

    const int tid = threadIdx.x, wid = tid >> 6, lane = tid & 63;
    const bf16* Ab = A + (long long)bz * batchA + (long long)bm * 64 * K;
    const bf16* Bb = B + (long long)bz * batchB + (long long)bn * 128 * K;

    extern __shared__ __align__(16) bf16 smem[];   // 24576 elems = 48KB
    bf16* sA = smem;            // [4][2048]
    bf16* sB = smem + 8192;     // [4][4096]

    const int srow = wid * 16 + (lane >> 2);          // 0..63
    const int scol = (lane & 3) * 8;
    const long long aoff = (long long)srow * K + scol;

    auto stage = [&](int buf, int kt) {
        const bf16* ga = Ab + (long long)kt * 32;
        const bf16* gb = Bb + (long long)kt * 32;
        gload_lds16(ga + aoff,            sA + buf * 2048 + (wid * 16) * 32);
        gload_lds16(gb + aoff,            sB + buf * 4096 + (wid * 16) * 32);
        gload_lds16(gb + aoff + 64LL * K, sB + buf * 4096 + (64 + wid * 16) * 32);
    };

    f32x4 acc[2][4];
#pragma unroll
    for (int m = 0; m < 2; ++m)
#pragma unroll
        for (int n = 0; n < 4; ++n) acc[m][n] = (f32x4){0.f, 0.f, 0.f, 0.f};

    const int npre = kTiles < 3 ? kTiles : 3;
    for (int t = 0; t < npre; ++t) stage(t, t);

    const int wr = wid >> 1, wc = wid & 1;
    const int arow = wr * 32 + (lane & 15);
    const int brow = wc * 64 + (lane & 15);
    const int koff = (lane >> 4) * 8;

    for (int kt = 0; kt < kTiles; ++kt) {
        const int rem = kTiles - 1 - kt;
        if (rem >= 2)      asm volatile("s_waitcnt vmcnt(6)" ::: "memory");
        else if (rem == 1) asm volatile("s_waitcnt vmcnt(3)" ::: "memory");
        else               asm volatile("s_waitcnt vmcnt(0)" ::: "memory");
        barrier_raw();
        if (kt + 3 < kTiles) stage((kt + 3) & 3, kt + 3);

        const int cur = kt & 3;
        const bf16* a = sA + cur * 2048;
        const bf16* b = sB + cur * 4096;
        bf16x8 af[2], bfr[4];
#pragma unroll
        for (int m = 0; m < 2; ++m)
            af[m] = *(const bf16x8*)&a[(arow + m * 16) * 32 + koff];
#pragma unroll
        for (int n = 0; n < 4; ++n)
            bfr[n] = *(const bf16x8*)&b[(brow + n * 16) * 32 + koff];
#pragma unroll
        for (int m = 0; m < 2; ++m)
#pragma unroll
            for (int n = 0; n < 4; ++n)
                acc[m][n] = __builtin_amdgcn_mfma_f32_16x16x32_bf16(af[m], bfr[n], acc[m][n], 0, 0, 0);
    }

    const int cr0 = bm * 64 + wr * 32 + (lane >> 4) * 4;
    const int cc0 = bn * 128 + wc * 64 + (lane & 15);
#pragma unroll
    for (int m = 0; m < 2; ++m) {
#pragma unroll
        for (int n = 0; n < 4; ++n) {
            const int col = cc0 + n * 16;
#pragma unroll
            for (int r = 0; r < 4; ++r) {
                const int row = cr0 + m * 16 + r;
                float v = acc[m][n][r];
                if (MODE == M_SCORES || MODE == M_PV) {
                    Cb[(long long)bz * batchC + (long long)row * N + col] = (bf16)v;
                } else { // M_OUT (final projection, fp32 + bias)
                    Cf[(long long)row * N + col] = v + bias[col];
                }
            }
        }
    }
}

// ---------------------------------------------------------------------------
__global__ __launch_bounds__(256)
void cvt_bf16_k(const float* __restrict__ in, bf16* __restrict__ out, int n4)
{
    int i = blockIdx.x * 256 + threadIdx.x;
    if (i >= n4) return;
    float4 f = ((const float4*)in)[i];
    bf16x4 o = { (bf16)f.x, (bf16)f.y, (bf16)f.z, (bf16)f.w };
    ((bf16x4*)out)[i] = o;
}

// out[l][c][r] = (bf16) in[l][r][c]   (n x n per layer, n mult of 32)
__global__ __launch_bounds__(256)
void transpose_cvt_k(const float* __restrict__ in, bf16* __restrict__ out, int n)
{
    __shared__ float t[32][33];
    const int l = blockIdx.z;
    const int r0 = blockIdx.y * 32, c0 = blockIdx.x * 32;
    const float* src = in + (long long)l * n * n;
    bf16* dst = out + (long long)l * n * n;
    const int tx = threadIdx.x & 31, ty = threadIdx.x >> 5;   // 32x8
#pragma unroll
    for (int i = 0; i < 32; i += 8)
        t[ty + i][tx] = src[(long long)(r0 + ty + i) * n + c0 + tx];
    __syncthreads();
#pragma unroll
    for (int i = 0; i < 32; i += 8)
        dst[(long long)(c0 + ty + i) * n + r0 + tx] = (bf16)t[tx][ty + i];
}

// merged bias: bm[l][a] = sum_j o2w[l][a][j]*o1b[l][j] + o2b[l][a]; one wave per (l,a)
__global__ __launch_bounds__(256)
void bias_merge_k(const float* __restrict__ o2w, const float* __restrict__ o1b,
                  const float* __restrict__ o2b, float* __restrict__ bm, int total)
{
    const int wid = threadIdx.x >> 6, lane = threadIdx.x & 63;
    const int idx = blockIdx.x * 4 + wid;
    if (idx >= total) return;
    const int l = idx / 768, a = idx - l * 768;
    const float* wrow = o2w + ((long long)l * 768 + a) * 768;
    const float* brow = o1b + (long long)l * 768;
    float s = 0.f;
#pragma unroll
    for (int j = 0; j < 12; ++j) {
        int c = j * 64 + lane;
        s += wrow[c] * brow[c];
    }
#pragma unroll
    for (int o = 32; o; o >>= 1) s += __shfl_down(s, o);
    if (lane == 0) bm[idx] = s + o2b[(long long)l * 768 + a];
}

__global__ __launch_bounds__(256)
void cond_proj_k(const float* __restrict__ label, const float* __restrict__ sw,
                 const float* __restrict__ bw, float* __restrict__ scale,
                 float* __restrict__ bias, int total)
{
    int idx = blockIdx.x * 256 + threadIdx.x;
    if (idx >= total) return;
    int l = idx / 6144;
    int rem = idx - l * 6144;
    int b = rem / 768, d = rem - (rem / 768) * 768;
    const float* lab = label + b * 17;
    const float* swp = sw + ((long long)l * 768 + d) * 17;
    const float* bwp = bw + ((long long)l * 768 + d) * 17;
    float s = 0.f, bb = 0.f;
#pragma unroll
    for (int c = 0; c < 17; ++c) { float lv = lab[c]; s += lv * swp[c]; bb += lv * bwp[c]; }
    scale[idx] = s;
    bias[idx]  = bb;
}

// h[b,s,:] = (s==0 ? sos : xe[b,s-1,:]) + pos_bias(s)
__global__ __launch_bounds__(256)
void shift_pos_k(const float* __restrict__ xe, const float* __restrict__ sos,
                 const float* __restrict__ p0, const float* __restrict__ p1,
                 const float* __restrict__ p2, float* __restrict__ h)
{
    const int s = blockIdx.x, b = blockIdx.y;
    const int i0 = s >> 8, i1 = (s >> 4) & 15, i2 = s & 15;
    const float* xr = xe + ((long long)b * 1024 + (s - 1)) * 768;
#pragma unroll
    for (int j = 0; j < 3; ++j) {
        const int d = j * 256 + threadIdx.x;
        float v = (s == 0) ? sos[d] : xr[d];
        float pbv = (d < 256) ? p0[i0 * 256 + d]
                  : (d < 512) ? p1[i1 * 256 + (d - 256)]
                              : p2[i2 * 256 + (d - 512)];
        h[((long long)b * 1024 + s) * 768 + d] = v + pbv;
    }
}

__global__ __launch_bounds__(256)
void cond_ln_k(const float* __restrict__ h, const float* __restrict__ scale,
               const float* __restrict__ bias, bf16* __restrict__ out)
{
    const long long row = (long long)blockIdx.y * 1024 + blockIdx.x;
    const int b = blockIdx.y;
    const float* hr = h + row * 768;
    float v[3], sum = 0.f, sq = 0.f;
#pragma unroll
    for (int j = 0; j < 3; ++j) {
        v[j] = hr[j * 256 + threadIdx.x];
        sum += v[j]; sq += v[j] * v[j];
    }
    __shared__ float sm[8];
#pragma unroll
    for (int o = 32; o; o >>= 1) { sum += __shfl_down(sum, o); sq += __shfl_down(sq, o); }
    const int wid = threadIdx.x >> 6;
    if ((threadIdx.x & 63) == 0) { sm[wid] = sum; sm[4 + wid] = sq; }
    __syncthreads();
    sum = sm[0] + sm[1] + sm[2] + sm[3];
    sq  = sm[4] + sm[5] + sm[6] + sm[7];
    const float mean = sum * (1.f / 768.f);
    const float var  = sq * (1.f / 768.f) - mean * mean;
    const float rs   = rsqrtf(var + 1e-6f);
    const float* sc = scale + (long long)b * 768;
    const float* bi = bias  + (long long)b * 768;
    bf16* orow = out + row * 768;
#pragma unroll
    for (int j = 0; j < 3; ++j) {
        const int d = j * 256 + threadIdx.x;
        orow[d] = (bf16)((v[j] - mean) * rs * (1.f + sc[d]) + bi[d]);
    }
}

// causal softmax over row i. Touches only cols < ceil64(i+1).
__global__ __launch_bounds__(256)
void softmax_k(bf16* __restrict__ P)
{
    const int i = blockIdx.x, b = blockIdx.y;
    bf16* row = P + ((long long)b * 1024 + i) * 1024;
    const int len = i + 1;
    const int lim = (i | 63) + 1;          // 64-col boundary PV can read up to
    float v[4], mx = -1e30f;
#pragma unroll
    for (int j = 0; j < 4; ++j) {
        int c = j * 256 + threadIdx.x;
        v[j] = (c < len) ? (float)row[c] : -1e30f;
        mx = fmaxf(mx, v[j]);
    }
    __shared__ float sm[8];
#pragma unroll
    for (int o = 32; o; o >>= 1) mx = fmaxf(mx, __shfl_down(mx, o));
    const int wid = threadIdx.x >> 6;
    if ((threadIdx.x & 63) == 0) sm[wid] = mx;
    __syncthreads();
    mx = fmaxf(fmaxf(sm[0], sm[1]), fmaxf(sm[2], sm[3]));
    float s = 0.f;
#pragma unroll
    for (int j = 0; j < 4; ++j) {
        v[j] = __expf(v[j] - mx);
        s += ((j * 256 + threadIdx.x) < len) ? v[j] : 0.f;
    }
#pragma unroll
    for (int o = 32; o; o >>= 1) s += __shfl_down(s, o);
    if ((threadIdx.x & 63) == 0) sm[4 + wid] = s;
    __syncthreads();
    s = sm[4] + sm[5] + sm[6] + sm[7];
    const float inv = 1.f / s;
#pragma unroll
    for (int j = 0; j < 4; ++j) {
        int c = j * 256 + threadIdx.x;
        if (c < lim) row[c] = (c < len) ? (bf16)(v[j] * inv) : (bf16)0.f;
    }
}

__global__ __launch_bounds__(256)
void fill_k(float* o, int n, float v)
{
    int i = blockIdx.x * 256 + threadIdx.x;
    if (i < n) o[i] = v;
}

// ---------------------------------------------------------------------------
extern "C" void kernel_launch(void* const* d_in, const int* in_sizes, int n_in,
                              void* d_out, int out_size, void* d_ws, size_t ws_size,
                              hipStream_t stream)
{
    (void)in_sizes; (void)n_in;
    const float* x     = (const float*)d_in[0];
    const float* label = (const float*)d_in[2];
    const float* dw    = (const float*)d_in[3];
    const float* db    = (const float*)d_in[4];
    const float* sos   = (const float*)d_in[5];
    const float* p0    = (const float*)d_in[6];
    const float* p1    = (const float*)d_in[7];
    const float* p2    = (const float*)d_in[8];
    const float* ln1sw = (const float*)d_in[9];
    const float* ln1bw = (const float*)d_in[10];
    const float* qkvw  = (const float*)d_in[11];
    const float* qkvb  = (const float*)d_in[12];
    const float* ao1w  = (const float*)d_in[13];
    const float* ao1b  = (const float*)d_in[14];
    const float* ao2w  = (const float*)d_in[15];
    const float* ao2b  = (const float*)d_in[16];
    const float* ln2sw = (const float*)d_in[17];
    const float* ln2bw = (const float*)d_in[18];
    const float* m1w   = (const float*)d_in[19];
    const float* m1b   = (const float*)d_in[20];
    const float* m2w   = (const float*)d_in[21];
    const float* m2b   = (const float*)d_in[22];
    const float* lnfsw = (const float*)d_in[23];
    const float* lnfbw = (const float*)d_in[24];
    const float* outw  = (const float*)d_in[25];
    const float* outb  = (const float*)d_in[26];
    float* out = (float*)d_out;

    char* p = (char*)d_ws;
    auto alloc = [&](size_t bytes) { void* r = (void*)p; p += (bytes + 255) & ~(size_t)255; return r; };
    float* h    = (float*)alloc(8192LL * 768 * 4);
    bf16*  hn   = (bf16*) alloc(8192LL * 768 * 2);
    bf16*  q    = (bf16*) alloc(8192LL * 768 * 2);
    bf16*  kbuf = (bf16*) alloc(8192LL * 768 * 2);
    bf16*  vT   = (bf16*) alloc(8192LL * 768 * 2);   // [B,768,1024]
    bf16*  P    = (bf16*) alloc(8LL * 1024 * 1024 * 2);
    bf16*  attn = (bf16*) alloc(8192LL * 768 * 2);
    bf16*  mb   = (bf16*) alloc(8192LL * 3072 * 2);
    bf16*  wout = (bf16*) alloc(1024LL * 768 * 2);
    bf16*  wmA  = (bf16*) alloc(12LL * 768 * 768 * 2);   // merged o2@o1, bf16
    float* bmA  = (float*)alloc(12LL * 768 * 4);         // merged o-bias
    float* s1   = (float*)alloc(12LL * 8 * 768 * 4);
    float* b1   = (float*)alloc(12LL * 8 * 768 * 4);
    float* s2   = (float*)alloc(12LL * 8 * 768 * 4);
    float* b2   = (float*)alloc(12LL * 8 * 768 * 4);
    float* sf   = (float*)alloc(8LL * 768 * 4);
    float* bfb  = (float*)alloc(8LL * 768 * 4);

    size_t base_needed = (size_t)(p - (char*)d_ws);
    if (base_needed + 16LL * 1024 * 1024 > ws_size) {
        fill_k<<<(out_size + 255) / 256, 256, 0, stream>>>(out, out_size, 1e9f);
        return;
    }

    // weight conversion: all-layers-at-once if ws allows, else per-layer
    const long long SZ_QKV = 2304LL * 768, SZ_O = 768LL * 768, SZ_M = 3072LL * 768;
    size_t all_bytes = (size_t)(12 * (SZ_QKV + 2 * SZ_M)) * 2;
    bool allw = ((size_t)(p - (char*)d_ws) + all_bytes + 4096 <= ws_size);

    bf16 *wqkvA, *wm1A, *wm2A;
    if (allw) {
        wqkvA = (bf16*)alloc(12 * SZ_QKV * 2);
        wm1A  = (bf16*)alloc(12 * SZ_M * 2);
        wm2A  = (bf16*)alloc(12 * SZ_M * 2);
    } else {
        wqkvA = (bf16*)alloc(SZ_QKV * 2);
        wm1A  = (bf16*)alloc(SZ_M * 2);
        wm2A  = (bf16*)alloc(SZ_M * 2);
    }

    // one-time scratch aliased onto regions unused until the layer loop:
    bf16*  xbf   = (bf16*)P;
    bf16*  dwbf  = (bf16*)P + 524288;
    bf16*  wo2bf = (bf16*)P + 1048576;
    float* xe    = (float*)mb;
    bf16*  o1t   = mb + 12582912;

    // --- one-time precompute ---
    cvt_bf16_k<<<1024 * 768 / 4 / 256, 256, 0, stream>>>(outw, wout, 1024 * 768 / 4);
    cond_proj_k<<<(12 * 8 * 768 + 255) / 256, 256, 0, stream>>>(label, ln1sw, ln1bw, s1, b1, 12 * 8 * 768);
    cond_proj_k<<<(12 * 8 * 768 + 255) / 256, 256, 0, stream>>>(label, ln2sw, ln2bw, s2, b2, 12 * 8 * 768);
    cond_proj_k<<<(8 * 768 + 255) / 256, 256, 0, stream>>>(label, lnfsw, lnfbw, sf, bfb, 8 * 768);

    if (allw) {
        cvt_bf16_k<<<(int)(12 * SZ_QKV / 4 / 256), 256, 0, stream>>>(qkvw, wqkvA, (int)(12 * SZ_QKV / 4));
        cvt_bf16_k<<<(int)(12 * SZ_M / 4 / 256),   256, 0, stream>>>(m1w,  wm1A,  (int)(12 * SZ_M / 4));
        cvt_bf16_k<<<(int)(12 * SZ_M / 4 / 256),   256, 0, stream>>>(m2w,  wm2A,  (int)(12 * SZ_M / 4));
    }

    // merged out-proj: Wm[l] = o2[l] @ o1[l]  (bf16), bm[l] = o2[l]@o1b[l] + o2b[l]
    cvt_bf16_k<<<(int)(12 * SZ_O / 4 / 256), 256, 0, stream>>>(ao2w, wo2bf, (int)(12 * SZ_O / 4));
    transpose_cvt_k<<<dim3(24, 24, 12), 256, 0, stream>>>(ao1w, o1t, 768);
    gemm_k<M_WM><<<dim3(6, 6, 12), 256, 65536, stream>>>(
        wo2bf, o1t, 768, 768, 768, SZ_O, SZ_O, SZ_O,
        nullptr, wmA, nullptr, nullptr, nullptr, nullptr);
    bias_merge_k<<<(12 * 768 + 3) / 4, 256, 0, stream>>>(ao2w, ao1b, ao2b, bmA, 12 * 768);

    // embed: x->bf16, xe = x @ dw^T + db (fp32), then shift+pos
    cvt_bf16_k<<<8192 * 64 / 4 / 256, 256, 0, stream>>>(x, xbf, 8192 * 64 / 4);
    cvt_bf16_k<<<768 * 64 / 4 / 256, 256, 0, stream>>>(dw, dwbf, 768 * 64 / 4);
    gemm_k<M_OUT><<<dim3(64, 6, 1), 256, 65536, stream>>>(
        xbf, dwbf, 8192, 768, 64, 0, 0, 0, db, nullptr, xe, nullptr, nullptr, nullptr);
    shift_pos_k<<<dim3(1024, 8), 256, 0, stream>>>(xe, sos, p0, p1, p2, h);

    for (int l = 0; l < 12; ++l) {
        bf16 *wqkv, *wm1, *wm2;
        if (allw) {
            wqkv = wqkvA + (long long)l * SZ_QKV;
            wm1  = wm1A  + (long long)l * SZ_M;
            wm2  = wm2A  + (long long)l * SZ_M;
        } else {
            wqkv = wqkvA; wm1 = wm1A; wm2 = wm2A;
            cvt_bf16_k<<<(int)(SZ_QKV / 4 / 256), 256, 0, stream>>>(qkvw + (long long)l * SZ_QKV, wqkv, (int)(SZ_QKV / 4));
            cvt_bf16_k<<<(int)(SZ_M / 4 / 256),   256, 0, stream>>>(m1w  + (long long)l * SZ_M,   wm1,  (int)(SZ_M / 4));
            cvt_bf16_k<<<(int)(SZ_M / 4 / 256),   256, 0, stream>>>(m2w  + (long long)l * SZ_M,   wm2,  (int)(SZ_M / 4));
        }

        cond_ln_k<<<dim3(1024, 8), 256, 0, stream>>>(h, s1 + (long long)l * 6144, b1 + (long long)l * 6144, hn);

        gemm_k<M_QKV><<<dim3(64, 18, 1), 256, 65536, stream>>>(
            hn, wqkv, 8192, 2304, 768, 0, 0, 0,
            qkvb + (long long)l * 2304, nullptr, nullptr, q, kbuf, vT);

        gemm64_k<M_SCORES><<<dim3(16, 8, 8), 256, 49152, stream>>>(
            q, kbuf, 1024, 1024, 768, 1024LL * 768, 1024LL * 768, 1024LL * 1024,
            nullptr, P, nullptr);

        softmax_k<<<dim3(1024, 8), 256, 0, stream>>>(P);

        gemm64_k<M_PV><<<dim3(16, 6, 8), 256, 49152, stream>>>(
            P, vT, 1024, 768, 1024, 1024LL * 1024, 768LL * 1024, 1024LL * 768,
            nullptr, attn, nullptr);

        // merged out-proj (o2@o1 fused), residual add into h
        gemm_k<M_RESID><<<dim3(64, 6, 1), 256, 65536, stream>>>(
            attn, wmA + (long long)l * SZ_O, 8192, 768, 768, 0, 0, 0,
            bmA + (long long)l * 768, nullptr, h, nullptr, nullptr, nullptr);

        cond_ln_k<<<dim3(1024, 8), 256, 0, stream>>>(h, s2 + (long long)l * 6144, b2 + (long long)l * 6144, hn);

        gemm_k<M_GELU><<<dim3(64, 24, 1), 256, 65536, stream>>>(
            hn, wm1, 8192, 3072, 768, 0, 0, 0,
            m1b + (long long)l * 3072, mb, nullptr, nullptr, nullptr, nullptr);

        gemm_k<M_RESID><<<dim3(64, 6, 1), 256, 65536, stream>>>(
            mb, wm2, 8192, 768, 3072, 0, 0, 0,
            m2b + (long long)l * 768, nullptr, h, nullptr, nullptr, nullptr);
    }

    cond_ln_k<<<dim3(1024, 8), 256, 0, stream>>>(h, sf, bfb, hn);
    gemm64_k<M_OUT><<<dim3(128, 8, 1), 256, 49152, stream>>>(
        hn, wout, 8192, 1024, 768, 0, 0, 0,
        outb, nullptr, out);
}

// Round 7
// 3905.477 us; speedup vs baseline: 1.2492x; 1.0191x over previous
//
#include <hip/hip_runtime.h>

typedef __bf16 bf16;
typedef __bf16 bf16x8 __attribute__((ext_vector_type(8)));
typedef __bf16 bf16x4 __attribute__((ext_vector_type(4)));
typedef float  f32x4  __attribute__((ext_vector_type(4)));

#define DEV __device__ __forceinline__

// async global->LDS, 16B per lane; lds dest must be wave-uniform base (HW adds lane*16)
DEV void gload_lds16(const bf16* g, bf16* l) {
    __builtin_amdgcn_global_load_lds(
        (__attribute__((address_space(1))) void*)g,
        (__attribute__((address_space(3))) void*)l, 16, 0, 0);
}

DEV void barrier_raw() {
    asm volatile("" ::: "memory");
    __builtin_amdgcn_s_barrier();
    asm volatile("" ::: "memory");
}

enum { M_QKV, M_SCORES, M_PV, M_RESID, M_GELU, M_OUT, M_WM };

// ---------------------------------------------------------------------------
// 128x128 tile GEMM, 3-buffer 2-ahead counted-vmcnt pipeline.
// C[m,n] = sum_k A[m,k]*B[n,k]; A:[M,K], B:[N,K] bf16 row-major.
// LDS: 3 x (8KB A + 8KB B) = 48KB dynamic -> 3 blocks/CU.
// ---------------------------------------------------------------------------
template<int MODE>
__global__ __launch_bounds__(256)
void gemm_k(const bf16* __restrict__ A, const bf16* __restrict__ B,
            int M, int N, int K,
            long long batchA, long long batchB, long long batchC,
            const float* __restrict__ bias,
            bf16* __restrict__ Cb, float* __restrict__ Cf,
            bf16* __restrict__ qp, bf16* __restrict__ kp, bf16* __restrict__ vp)
{
    const int bm = blockIdx.x, bn = blockIdx.y, bz = blockIdx.z;
    const int kTiles = K >> 5;

    const int tid = threadIdx.x, wid = tid >> 6, lane = tid & 63;
    const bf16* Ab = A + (long long)bz * batchA + (long long)bm * 128 * K;
    const bf16* Bb = B + (long long)bz * batchB + (long long)bn * 128 * K;

    extern __shared__ __align__(16) bf16 smem[];   // 24576 elems = 48KB
    bf16* sA = smem;            // [3][4096]
    bf16* sB = smem + 12288;    // [3][4096]

    const int srow = wid * 16 + (lane >> 2);
    const int scol = (lane & 3) * 8;
    const long long aoff = (long long)srow * K + scol;

    auto stage = [&](int buf, int kt) {
        const bf16* ga = Ab + (long long)kt * 32;
        const bf16* gb = Bb + (long long)kt * 32;
        bf16* a = sA + buf * 4096;
        bf16* b = sB + buf * 4096;
        gload_lds16(ga + aoff,            a + (wid * 16) * 32);
        gload_lds16(ga + aoff + 64LL * K, a + (64 + wid * 16) * 32);
        gload_lds16(gb + aoff,            b + (wid * 16) * 32);
        gload_lds16(gb + aoff + 64LL * K, b + (64 + wid * 16) * 32);
    };

    f32x4 acc[4][4];
#pragma unroll
    for (int m = 0; m < 4; ++m)
#pragma unroll
        for (int n = 0; n < 4; ++n) acc[m][n] = (f32x4){0.f, 0.f, 0.f, 0.f};

    const int npre = kTiles < 2 ? kTiles : 2;
    for (int t = 0; t < npre; ++t) stage(t, t);

    const int wr = wid >> 1, wc = wid & 1;
    const int arow = wr * 64 + (lane & 15);
    const int brow = wc * 64 + (lane & 15);
    const int koff = (lane >> 4) * 8;

    int cur = 0;
    for (int kt = 0; kt < kTiles; ++kt) {
        if (kt + 1 < kTiles) asm volatile("s_waitcnt vmcnt(4)" ::: "memory");
        else                 asm volatile("s_waitcnt vmcnt(0)" ::: "memory");
        barrier_raw();   // all waves: stage(kt) visible; iter kt-1 reads done
        if (kt + 2 < kTiles) {
            int ib = cur - 1; if (ib < 0) ib = 2;   // (cur+2)%3
            stage(ib, kt + 2);
        }

        const bf16* a = sA + cur * 4096;
        const bf16* b = sB + cur * 4096;
        bf16x8 af[4], bfr[4];
#pragma unroll
        for (int m = 0; m < 4; ++m)
            af[m] = *(const bf16x8*)&a[(arow + m * 16) * 32 + koff];
#pragma unroll
        for (int n = 0; n < 4; ++n)
            bfr[n] = *(const bf16x8*)&b[(brow + n * 16) * 32 + koff];
#pragma unroll
        for (int m = 0; m < 4; ++m)
#pragma unroll
            for (int n = 0; n < 4; ++n)
                acc[m][n] = __builtin_amdgcn_mfma_f32_16x16x32_bf16(af[m], bfr[n], acc[m][n], 0, 0, 0);

        cur = (cur == 2) ? 0 : cur + 1;
    }

    // C/D layout: col = lane&15, row = (lane>>4)*4 + r   [learn_hip m89]
    const int cr0 = bm * 128 + wr * 64 + (lane >> 4) * 4;
    const int cc0 = bn * 128 + wc * 64 + (lane & 15);
#pragma unroll
    for (int m = 0; m < 4; ++m) {
#pragma unroll
        for (int n = 0; n < 4; ++n) {
            const int col = cc0 + n * 16;
#pragma unroll
            for (int r = 0; r < 4; ++r) {
                const int row = cr0 + m * 16 + r;
                float v = acc[m][n][r];
                if (MODE == M_QKV) {
                    v += bias[col];
                    int hd = col / 192, rr = col % 192;
                    int b2 = row >> 10, s = row & 1023;
                    if (rr < 64)
                        qp[(long long)row * 768 + hd * 64 + rr] = (bf16)(v * 0.03608439182435161f);
                    else if (rr < 128)
                        kp[(long long)row * 768 + hd * 64 + (rr - 64)] = (bf16)v;
                    else
                        vp[((long long)b2 * 768 + hd * 64 + (rr - 128)) * 1024 + s] = (bf16)v;
                } else if (MODE == M_GELU) {
                    float xg = v + bias[col];
                    Cb[(long long)row * N + col] = (bf16)(xg / (1.f + __expf(-1.702f * xg)));
                } else if (MODE == M_RESID) {
                    long long idx = (long long)row * N + col;
                    Cf[idx] += v + bias[col];
                } else if (MODE == M_WM) {
                    Cb[(long long)bz * batchC + (long long)row * N + col] = (bf16)v;
                } else { // M_OUT (fp32 + bias)
                    Cf[(long long)row * N + col] = v + bias[col];
                }
            }
        }
    }
}

// ---------------------------------------------------------------------------
// 64x128 tile GEMM, 3-buffer 2-ahead pipeline (3 gloads/stage), 36KB LDS
// -> 4 blocks/CU. For shallow-N GEMMs (mlp2, o-merged, final out) and
// scores/PV (causal granularity).
// ---------------------------------------------------------------------------
template<int MODE>
__global__ __launch_bounds__(256)
void gemm64_k(const bf16* __restrict__ A, const bf16* __restrict__ B,
              int M, int N, int K,
              long long batchA, long long batchB, long long batchC,
              const float* __restrict__ bias,
              bf16* __restrict__ Cb, float* __restrict__ Cf)
{
    const int bm = blockIdx.x, bn = blockIdx.y, bz = blockIdx.z;
    if (MODE == M_SCORES && 2 * bn > bm) return;     // fully-masked tile
    int kTiles = K >> 5;
    if (MODE == M_PV) {                              // P[:,k]==0 for k>row
        int lim = 2 * bm + 2;
        if (lim < kTiles) kTiles = lim;
    }

    const int tid = threadIdx.x, wid = tid >> 6, lane = tid & 63;
    const bf16* Ab = A + (long long)bz * batchA + (long long)bm * 64 * K;
    const bf16* Bb = B + (long long)bz * batchB + (long long)bn * 128 * K;

    extern __shared__ __align__(16) bf16 smem[];   // 18432 elems = 36KB
    bf16* sA = smem;            // [3][2048]
    bf16* sB = smem + 6144;     // [3][4096]

    const int srow = wid * 16 + (lane >> 2);          // 0..63
    const int scol = (lane & 3) * 8;
    const long long aoff = (long long)srow * K + scol;

    auto stage = [&](int buf, int kt) {
        const bf16* ga = Ab + (long long)kt * 32;
        const bf16* gb = Bb + (long long)kt * 32;
        gload_lds16(ga + aoff,            sA + buf * 2048 + (wid * 16) * 32);
        gload_lds16(gb + aoff,            sB + buf * 4096 + (wid * 16) * 32);
        gload_lds16(gb + aoff + 64LL * K, sB + buf * 4096 + (64 + wid * 16) * 32);
    };

    f32x4 acc[2][4];
#pragma unroll
    for (int m = 0; m < 2; ++m)
#pragma unroll
        for (int n = 0; n < 4; ++n) acc[m][n] = (f32x4){0.f, 0.f, 0.f, 0.f};

    const int npre = kTiles < 2 ? kTiles : 2;
    for (int t = 0; t < npre; ++t) stage(t, t);

    const int wr = wid >> 1, wc = wid & 1;
    const int arow = wr * 32 + (lane & 15);
    const int brow = wc * 64 + (lane & 15);
    const int koff = (lane >> 4) * 8;

    int cur = 0;
    for (int kt = 0; kt < kTiles; ++kt) {
        if (kt + 1 < kTiles) asm volatile("s_waitcnt vmcnt(3)" ::: "memory");
        else                 asm volatile("s_waitcnt vmcnt(0)" ::: "memory");
        barrier_raw();
        if (kt + 2 < kTiles) {
            int ib = cur - 1; if (ib < 0) ib = 2;   // (cur+2)%3
            stage(ib, kt + 2);
        }

        const bf16* a = sA + cur * 2048;
        const bf16* b = sB + cur * 4096;
        bf16x8 af[2], bfr[4];
#pragma unroll
        for (int m = 0; m < 2; ++m)
            af[m] = *(const bf16x8*)&a[(arow + m * 16) * 32 + koff];
#pragma unroll
        for (int n = 0; n < 4; ++n)
            bfr[n] = *(const bf16x8*)&b[(brow + n * 16) * 32 + koff];
#pragma unroll
        for (int m = 0; m < 2; ++m)
#pragma unroll
            for (int n = 0; n < 4; ++n)
                acc[m][n] = __builtin_amdgcn_mfma_f32_16x16x32_bf16(af[m], bfr[n], acc[m][n], 0, 0, 0);

        cur = (cur == 2) ? 0 : cur + 1;
    }

    const int cr0 = bm * 64 + wr * 32 + (lane >> 4) * 4;
    const int cc0 = bn * 128 + wc * 64 + (lane & 15);
#pragma unroll
    for (int m = 0; m < 2; ++m) {
#pragma unroll
        for (int n = 0; n < 4; ++n) {
            const int col = cc0 + n * 16;
#pragma unroll
            for (int r = 0; r < 4; ++r) {
                const int row = cr0 + m * 16 + r;
                float v = acc[m][n][r];
                if (MODE == M_SCORES || MODE == M_PV) {
                    Cb[(long long)bz * batchC + (long long)row * N + col] = (bf16)v;
                } else if (MODE == M_RESID) {
                    long long idx = (long long)row * N + col;
                    Cf[idx] += v + bias[col];
                } else { // M_OUT (fp32 + bias)
                    Cf[(long long)row * N + col] = v + bias[col];
                }
            }
        }
    }
}

// ---------------------------------------------------------------------------
__global__ __launch_bounds__(256)
void cvt_bf16_k(const float* __restrict__ in, bf16* __restrict__ out, int n4)
{
    int i = blockIdx.x * 256 + threadIdx.x;
    if (i >= n4) return;
    float4 f = ((const float4*)in)[i];
    bf16x4 o = { (bf16)f.x, (bf16)f.y, (bf16)f.z, (bf16)f.w };
    ((bf16x4*)out)[i] = o;
}

// out[l][c][r] = (bf16) in[l][r][c]   (n x n per layer, n mult of 32)
__global__ __launch_bounds__(256)
void transpose_cvt_k(const float* __restrict__ in, bf16* __restrict__ out, int n)
{
    __shared__ float t[32][33];
    const int l = blockIdx.z;
    const int r0 = blockIdx.y * 32, c0 = blockIdx.x * 32;
    const float* src = in + (long long)l * n * n;
    bf16* dst = out + (long long)l * n * n;
    const int tx = threadIdx.x & 31, ty = threadIdx.x >> 5;   // 32x8
#pragma unroll
    for (int i = 0; i < 32; i += 8)
        t[ty + i][tx] = src[(long long)(r0 + ty + i) * n + c0 + tx];
    __syncthreads();
#pragma unroll
    for (int i = 0; i < 32; i += 8)
        dst[(long long)(c0 + ty + i) * n + r0 + tx] = (bf16)t[tx][ty + i];
}

// merged bias: bm[l][a] = sum_j o2w[l][a][j]*o1b[l][j] + o2b[l][a]; one wave per (l,a)
__global__ __launch_bounds__(256)
void bias_merge_k(const float* __restrict__ o2w, const float* __restrict__ o1b,
                  const float* __restrict__ o2b, float* __restrict__ bm, int total)
{
    const int wid = threadIdx.x >> 6, lane = threadIdx.x & 63;
    const int idx = blockIdx.x * 4 + wid;
    if (idx >= total) return;
    const int l = idx / 768, a = idx - l * 768;
    const float* wrow = o2w + ((long long)l * 768 + a) * 768;
    const float* brow = o1b + (long long)l * 768;
    float s = 0.f;
#pragma unroll
    for (int j = 0; j < 12; ++j) {
        int c = j * 64 + lane;
        s += wrow[c] * brow[c];
    }
#pragma unroll
    for (int o = 32; o; o >>= 1) s += __shfl_down(s, o);
    if (lane == 0) bm[idx] = s + o2b[(long long)l * 768 + a];
}

__global__ __launch_bounds__(256)
void cond_proj_k(const float* __restrict__ label, const float* __restrict__ sw,
                 const float* __restrict__ bw, float* __restrict__ scale,
                 float* __restrict__ bias, int total)
{
    int idx = blockIdx.x * 256 + threadIdx.x;
    if (idx >= total) return;
    int l = idx / 6144;
    int rem = idx - l * 6144;
    int b = rem / 768, d = rem - (rem / 768) * 768;
    const float* lab = label + b * 17;
    const float* swp = sw + ((long long)l * 768 + d) * 17;
    const float* bwp = bw + ((long long)l * 768 + d) * 17;
    float s = 0.f, bb = 0.f;
#pragma unroll
    for (int c = 0; c < 17; ++c) { float lv = lab[c]; s += lv * swp[c]; bb += lv * bwp[c]; }
    scale[idx] = s;
    bias[idx]  = bb;
}

// h[b,s,:] = (s==0 ? sos : xe[b,s-1,:]) + pos_bias(s)
__global__ __launch_bounds__(256)
void shift_pos_k(const float* __restrict__ xe, const float* __restrict__ sos,
                 const float* __restrict__ p0, const float* __restrict__ p1,
                 const float* __restrict__ p2, float* __restrict__ h)
{
    const int s = blockIdx.x, b = blockIdx.y;
    const int i0 = s >> 8, i1 = (s >> 4) & 15, i2 = s & 15;
    const float* xr = xe + ((long long)b * 1024 + (s - 1)) * 768;
#pragma unroll
    for (int j = 0; j < 3; ++j) {
        const int d = j * 256 + threadIdx.x;
        float v = (s == 0) ? sos[d] : xr[d];
        float pbv = (d < 256) ? p0[i0 * 256 + d]
                  : (d < 512) ? p1[i1 * 256 + (d - 256)]
                              : p2[i2 * 256 + (d - 512)];
        h[((long long)b * 1024 + s) * 768 + d] = v + pbv;
    }
}

__global__ __launch_bounds__(256)
void cond_ln_k(const float* __restrict__ h, const float* __restrict__ scale,
               const float* __restrict__ bias, bf16* __restrict__ out)
{
    const long long row = (long long)blockIdx.y * 1024 + blockIdx.x;
    const int b = blockIdx.y;
    const float* hr = h + row * 768;
    float v[3], sum = 0.f, sq = 0.f;
#pragma unroll
    for (int j = 0; j < 3; ++j) {
        v[j] = hr[j * 256 + threadIdx.x];
        sum += v[j]; sq += v[j] * v[j];
    }
    __shared__ float sm[8];
#pragma unroll
    for (int o = 32; o; o >>= 1) { sum += __shfl_down(sum, o); sq += __shfl_down(sq, o); }
    const int wid = threadIdx.x >> 6;
    if ((threadIdx.x & 63) == 0) { sm[wid] = sum; sm[4 + wid] = sq; }
    __syncthreads();
    sum = sm[0] + sm[1] + sm[2] + sm[3];
    sq  = sm[4] + sm[5] + sm[6] + sm[7];
    const float mean = sum * (1.f / 768.f);
    const float var  = sq * (1.f / 768.f) - mean * mean;
    const float rs   = rsqrtf(var + 1e-6f);
    const float* sc = scale + (long long)b * 768;
    const float* bi = bias  + (long long)b * 768;
    bf16* orow = out + row * 768;
#pragma unroll
    for (int j = 0; j < 3; ++j) {
        const int d = j * 256 + threadIdx.x;
        orow[d] = (bf16)((v[j] - mean) * rs * (1.f + sc[d]) + bi[d]);
    }
}

// causal softmax over row i. Touches only cols < ceil64(i+1).
__global__ __launch_bounds__(256)
void softmax_k(bf16* __restrict__ P)
{
    const int i = blockIdx.x, b = blockIdx.y;
    bf16* row = P + ((long long)b * 1024 + i) * 1024;
    const int len = i + 1;
    const int lim = (i | 63) + 1;          // 64-col boundary PV can read up to
    float v[4], mx = -1e30f;
#pragma unroll
    for (int j = 0; j < 4; ++j) {
        int c = j * 256 + threadIdx.x;
        v[j] = (c < len) ? (float)row[c] : -1e30f;
        mx = fmaxf(mx, v[j]);
    }
    __shared__ float sm[8];
#pragma unroll
    for (int o = 32; o; o >>= 1) mx = fmaxf(mx, __shfl_down(mx, o));
    const int wid = threadIdx.x >> 6;
    if ((threadIdx.x & 63) == 0) sm[wid] = mx;
    __syncthreads();
    mx = fmaxf(fmaxf(sm[0], sm[1]), fmaxf(sm[2], sm[3]));
    float s = 0.f;
#pragma unroll
    for (int j = 0; j < 4; ++j) {
        v[j] = __expf(v[j] - mx);
        s += ((j * 256 + threadIdx.x) < len) ? v[j] : 0.f;
    }
#pragma unroll
    for (int o = 32; o; o >>= 1) s += __shfl_down(s, o);
    if ((threadIdx.x & 63) == 0) sm[4 + wid] = s;
    __syncthreads();
    s = sm[4] + sm[5] + sm[6] + sm[7];
    const float inv = 1.f / s;
#pragma unroll
    for (int j = 0; j < 4; ++j) {
        int c = j * 256 + threadIdx.x;
        if (c < lim) row[c] = (c < len) ? (bf16)(v[j] * inv) : (bf16)0.f;
    }
}

__global__ __launch_bounds__(256)
void fill_k(float* o, int n, float v)
{
    int i = blockIdx.x * 256 + threadIdx.x;
    if (i < n) o[i] = v;
}

// ---------------------------------------------------------------------------
extern "C" void kernel_launch(void* const* d_in, const int* in_sizes, int n_in,
                              void* d_out, int out_size, void* d_ws, size_t ws_size,
                              hipStream_t stream)
{
    (void)in_sizes; (void)n_in;
    const float* x     = (const float*)d_in[0];
    const float* label = (const float*)d_in[2];
    const float* dw    = (const float*)d_in[3];
    const float* db    = (const float*)d_in[4];
    const float* sos   = (const float*)d_in[5];
    const float* p0    = (const float*)d_in[6];
    const float* p1    = (const float*)d_in[7];
    const float* p2    = (const float*)d_in[8];
    const float* ln1sw = (const float*)d_in[9];
    const float* ln1bw = (const float*)d_in[10];
    const float* qkvw  = (const float*)d_in[11];
    const float* qkvb  = (const float*)d_in[12];
    const float* ao1w  = (const float*)d_in[13];
    const float* ao1b  = (const float*)d_in[14];
    const float* ao2w  = (const float*)d_in[15];
    const float* ao2b  = (const float*)d_in[16];
    const float* ln2sw = (const float*)d_in[17];
    const float* ln2bw = (const float*)d_in[18];
    const float* m1w   = (const float*)d_in[19];
    const float* m1b   = (const float*)d_in[20];
    const float* m2w   = (const float*)d_in[21];
    const float* m2b   = (const float*)d_in[22];
    const float* lnfsw = (const float*)d_in[23];
    const float* lnfbw = (const float*)d_in[24];
    const float* outw  = (const float*)d_in[25];
    const float* outb  = (const float*)d_in[26];
    float* out = (float*)d_out;

    char* p = (char*)d_ws;
    auto alloc = [&](size_t bytes) { void* r = (void*)p; p += (bytes + 255) & ~(size_t)255; return r; };
    float* h    = (float*)alloc(8192LL * 768 * 4);
    bf16*  hn   = (bf16*) alloc(8192LL * 768 * 2);
    bf16*  q    = (bf16*) alloc(8192LL * 768 * 2);
    bf16*  kbuf = (bf16*) alloc(8192LL * 768 * 2);
    bf16*  vT   = (bf16*) alloc(8192LL * 768 * 2);   // [B,768,1024]
    bf16*  P    = (bf16*) alloc(8LL * 1024 * 1024 * 2);
    bf16*  attn = (bf16*) alloc(8192LL * 768 * 2);
    bf16*  mb   = (bf16*) alloc(8192LL * 3072 * 2);
    bf16*  wout = (bf16*) alloc(1024LL * 768 * 2);
    bf16*  wmA  = (bf16*) alloc(12LL * 768 * 768 * 2);   // merged o2@o1, bf16
    float* bmA  = (float*)alloc(12LL * 768 * 4);         // merged o-bias
    float* s1   = (float*)alloc(12LL * 8 * 768 * 4);
    float* b1   = (float*)alloc(12LL * 8 * 768 * 4);
    float* s2   = (float*)alloc(12LL * 8 * 768 * 4);
    float* b2   = (float*)alloc(12LL * 8 * 768 * 4);
    float* sf   = (float*)alloc(8LL * 768 * 4);
    float* bfb  = (float*)alloc(8LL * 768 * 4);

    size_t base_needed = (size_t)(p - (char*)d_ws);
    if (base_needed + 16LL * 1024 * 1024 > ws_size) {
        fill_k<<<(out_size + 255) / 256, 256, 0, stream>>>(out, out_size, 1e9f);
        return;
    }

    // weight conversion: all-layers-at-once if ws allows, else per-layer
    const long long SZ_QKV = 2304LL * 768, SZ_O = 768LL * 768, SZ_M = 3072LL * 768;
    size_t all_bytes = (size_t)(12 * (SZ_QKV + 2 * SZ_M)) * 2;
    bool allw = ((size_t)(p - (char*)d_ws) + all_bytes + 4096 <= ws_size);

    bf16 *wqkvA, *wm1A, *wm2A;
    if (allw) {
        wqkvA = (bf16*)alloc(12 * SZ_QKV * 2);
        wm1A  = (bf16*)alloc(12 * SZ_M * 2);
        wm2A  = (bf16*)alloc(12 * SZ_M * 2);
    } else {
        wqkvA = (bf16*)alloc(SZ_QKV * 2);
        wm1A  = (bf16*)alloc(SZ_M * 2);
        wm2A  = (bf16*)alloc(SZ_M * 2);
    }

    // one-time scratch aliased onto regions unused until the layer loop:
    bf16*  xbf   = (bf16*)P;
    bf16*  dwbf  = (bf16*)P + 524288;
    bf16*  wo2bf = (bf16*)P + 1048576;
    float* xe    = (float*)mb;
    bf16*  o1t   = mb + 12582912;

    // --- one-time precompute ---
    cvt_bf16_k<<<1024 * 768 / 4 / 256, 256, 0, stream>>>(outw, wout, 1024 * 768 / 4);
    cond_proj_k<<<(12 * 8 * 768 + 255) / 256, 256, 0, stream>>>(label, ln1sw, ln1bw, s1, b1, 12 * 8 * 768);
    cond_proj_k<<<(12 * 8 * 768 + 255) / 256, 256, 0, stream>>>(label, ln2sw, ln2bw, s2, b2, 12 * 8 * 768);
    cond_proj_k<<<(8 * 768 + 255) / 256, 256, 0, stream>>>(label, lnfsw, lnfbw, sf, bfb, 8 * 768);

    if (allw) {
        cvt_bf16_k<<<(int)(12 * SZ_QKV / 4 / 256), 256, 0, stream>>>(qkvw, wqkvA, (int)(12 * SZ_QKV / 4));
        cvt_bf16_k<<<(int)(12 * SZ_M / 4 / 256),   256, 0, stream>>>(m1w,  wm1A,  (int)(12 * SZ_M / 4));
        cvt_bf16_k<<<(int)(12 * SZ_M / 4 / 256),   256, 0, stream>>>(m2w,  wm2A,  (int)(12 * SZ_M / 4));
    }

    // merged out-proj: Wm[l] = o2[l] @ o1[l]  (bf16), bm[l] = o2[l]@o1b[l] + o2b[l]
    cvt_bf16_k<<<(int)(12 * SZ_O / 4 / 256), 256, 0, stream>>>(ao2w, wo2bf, (int)(12 * SZ_O / 4));
    transpose_cvt_k<<<dim3(24, 24, 12), 256, 0, stream>>>(ao1w, o1t, 768);
    gemm_k<M_WM><<<dim3(6, 6, 12), 256, 49152, stream>>>(
        wo2bf, o1t, 768, 768, 768, SZ_O, SZ_O, SZ_O,
        nullptr, wmA, nullptr, nullptr, nullptr, nullptr);
    bias_merge_k<<<(12 * 768 + 3) / 4, 256, 0, stream>>>(ao2w, ao1b, ao2b, bmA, 12 * 768);

    // embed: x->bf16, xe = x @ dw^T + db (fp32), then shift+pos
    cvt_bf16_k<<<8192 * 64 / 4 / 256, 256, 0, stream>>>(x, xbf, 8192 * 64 / 4);
    cvt_bf16_k<<<768 * 64 / 4 / 256, 256, 0, stream>>>(dw, dwbf, 768 * 64 / 4);
    gemm_k<M_OUT><<<dim3(64, 6, 1), 256, 49152, stream>>>(
        xbf, dwbf, 8192, 768, 64, 0, 0, 0, db, nullptr, xe, nullptr, nullptr, nullptr);
    shift_pos_k<<<dim3(1024, 8), 256, 0, stream>>>(xe, sos, p0, p1, p2, h);

    for (int l = 0; l < 12; ++l) {
        bf16 *wqkv, *wm1, *wm2;
        if (allw) {
            wqkv = wqkvA + (long long)l * SZ_QKV;
            wm1  = wm1A  + (long long)l * SZ_M;
            wm2  = wm2A  + (long long)l * SZ_M;
        } else {
            wqkv = wqkvA; wm1 = wm1A; wm2 = wm2A;
            cvt_bf16_k<<<(int)(SZ_QKV / 4 / 256), 256, 0, stream>>>(qkvw + (long long)l * SZ_QKV, wqkv, (int)(SZ_QKV / 4));
            cvt_bf16_k<<<(int)(SZ_M / 4 / 256),   256, 0, stream>>>(m1w  + (long long)l * SZ_M,   wm1,  (int)(SZ_M / 4));
            cvt_bf16_k<<<(int)(SZ_M / 4 / 256),   256, 0, stream>>>(m2w  + (long long)l * SZ_M,   wm2,  (int)(SZ_M / 4));
        }

        cond_ln_k<<<dim3(1024, 8), 256, 0, stream>>>(h, s1 + (long long)l * 6144, b1 + (long long)l * 6144, hn);

        gemm_k<M_QKV><<<dim3(64, 18, 1), 256, 49152, stream>>>(
            hn, wqkv, 8192, 2304, 768, 0, 0, 0,
            qkvb + (long long)l * 2304, nullptr, nullptr, q, kbuf, vT);

        gemm64_k<M_SCORES><<<dim3(16, 8, 8), 256, 36864, stream>>>(
            q, kbuf, 1024, 1024, 768, 1024LL * 768, 1024LL * 768, 1024LL * 1024,
            nullptr, P, nullptr);

        softmax_k<<<dim3(1024, 8), 256, 0, stream>>>(P);

        gemm64_k<M_PV><<<dim3(16, 6, 8), 256, 36864, stream>>>(
            P, vT, 1024, 768, 1024, 1024LL * 1024, 768LL * 1024, 1024LL * 768,
            nullptr, attn, nullptr);

        // merged out-proj (o2@o1 fused), residual add into h  (768-block grid)
        gemm64_k<M_RESID><<<dim3(128, 6, 1), 256, 36864, stream>>>(
            attn, wmA + (long long)l * SZ_O, 8192, 768, 768, 0, 0, 0,
            bmA + (long long)l * 768, nullptr, h);

        cond_ln_k<<<dim3(1024, 8), 256, 0, stream>>>(h, s2 + (long long)l * 6144, b2 + (long long)l * 6144, hn);

        gemm_k<M_GELU><<<dim3(64, 24, 1), 256, 49152, stream>>>(
            hn, wm1, 8192, 3072, 768, 0, 0, 0,
            m1b + (long long)l * 3072, mb, nullptr, nullptr, nullptr, nullptr);

        // mlp2, residual add into h  (768-block grid, 4 blocks/CU capacity)
        gemm64_k<M_RESID><<<dim3(128, 6, 1), 256, 36864, stream>>>(
            mb, wm2, 8192, 768, 3072, 0, 0, 0,
            m2b + (long long)l * 768, nullptr, h);
    }

    cond_ln_k<<<dim3(1024, 8), 256, 0, stream>>>(h, sf, bfb, hn);
    gemm64_k<M_OUT><<<dim3(128, 8, 1), 256, 36864, stream>>>(
        hn, wout, 8192, 1024, 768, 0, 0, 0,
        outb, nullptr, out);
}